// Round 1
// baseline (713.252 us; speedup 1.0000x reference)
//
#include <hip/hip_runtime.h>

#define FN 32
#define FE 16
#define HID 64
#define HEADS 4
#define CHC 64
// H*C = 256

// x1 = relu(x @ wn + bn), 4 nodes per 256-thread block
__global__ __launch_bounds__(256) void k_x1(const float* __restrict__ x,
    const float* __restrict__ wn, const float* __restrict__ bn,
    float* __restrict__ x1, int n)
{
  int t = threadIdx.x; int w = t >> 6; int lane = t & 63;
  int v = blockIdx.x * 4 + w;
  __shared__ float xs[4][FN];
  if (v < n && lane < FN) xs[w][lane] = x[(size_t)v * FN + lane];
  __syncthreads();
  if (v >= n) return;
  float acc = bn[lane];
  #pragma unroll
  for (int k = 0; k < FN; k++) acc += xs[w][k] * wn[k * HID + lane];
  x1[(size_t)v * HID + lane] = fmaxf(acc, 0.f);
}

__global__ __launch_bounds__(256) void k_deg(const int* __restrict__ dst,
                                             int* __restrict__ deg, int E)
{
  int e = blockIdx.x * 256 + threadIdx.x;
  if (e < E) atomicAdd(&deg[dst[e]], 1);
}

// exclusive prefix sum of deg -> rowptr[0..n], single block
__global__ __launch_bounds__(1024) void k_scan(const int* __restrict__ deg,
                                               int* __restrict__ rowptr, int n)
{
  __shared__ int buf[1024];
  __shared__ int carry;
  int t = threadIdx.x;
  if (t == 0) carry = 0;
  __syncthreads();
  for (int base = 0; base < n; base += 1024) {
    int i = base + t;
    int v = (i < n) ? deg[i] : 0;
    buf[t] = v;
    __syncthreads();
    for (int off = 1; off < 1024; off <<= 1) {
      int add = (t >= off) ? buf[t - off] : 0;
      __syncthreads();
      buf[t] += add;
      __syncthreads();
    }
    if (i < n) rowptr[i] = carry + buf[t] - v;
    __syncthreads();
    if (t == 0) carry += buf[1023];
    __syncthreads();
  }
  if (t == 0) rowptr[n] = carry;
}

__global__ __launch_bounds__(256) void k_fill(const int* __restrict__ dst,
    const int* __restrict__ rowptr, int* __restrict__ cnt,
    int* __restrict__ eid, int E)
{
  int e = blockIdx.x * 256 + threadIdx.x;
  if (e < E) {
    int d = dst[e];
    int pos = rowptr[d] + atomicAdd(&cnt[d], 1);
    eid[pos] = e;
  }
}

// mean of relu(edge_attr @ we + be) over incoming edges per node (ea recomputed on the fly)
__global__ __launch_bounds__(256) void k_mean(const float* __restrict__ eattr,
    const float* __restrict__ we, const float* __restrict__ be,
    const int* __restrict__ rowptr, const int* __restrict__ eidArr,
    float* __restrict__ mean_ea, int n)
{
  int t = threadIdx.x; int w = t >> 6; int c = t & 63;
  int v = blockIdx.x * 4 + w;
  if (v >= n) return;
  int r0 = rowptr[v], r1 = rowptr[v + 1];
  float s = 0.f;
  for (int j = r0; j < r1; j++) {
    int e = eidArr[j];
    float acc = be[c];
    #pragma unroll
    for (int k = 0; k < FE; k++) acc += eattr[(size_t)e * FE + k] * we[k * HID + c];
    s += fmaxf(acc, 0.f);
  }
  mean_ea[(size_t)v * HID + c] = s / fmaxf((float)(r1 - r0), 1.f);
}

// vE[l][k][h] = sum_c line_l[k][h*64+c] * ae_l[h][c]   (512 values total)
__global__ void k_vE(const float* __restrict__ line1, const float* __restrict__ ae1,
                     const float* __restrict__ line2, const float* __restrict__ ae2,
                     float* __restrict__ vE)
{
  int t = blockIdx.x * blockDim.x + threadIdx.x;
  if (t >= 512) return;
  int l = t >> 8; int c = (t >> 2) & 63; int hd = t & 3;
  const float* line = l ? line2 : line1;
  const float* ae   = l ? ae2 : ae1;
  float acc = 0.f;
  for (int cc = 0; cc < CHC; cc++)
    acc += line[c * (HEADS * CHC) + hd * CHC + cc] * ae[hd * CHC + cc];
  vE[t] = acc;
}

// a_edge for both layers: aeg_l[e][h] = relu(ea_f[e]) . vE_l  (ea recomputed; self-loops read mean_ea)
__global__ __launch_bounds__(256) void k_aeg(const float* __restrict__ eattr,
    const float* __restrict__ we, const float* __restrict__ be,
    const float* __restrict__ mean_ea, const float* __restrict__ vE,
    float* __restrict__ aeg1, float* __restrict__ aeg2, int E, int n)
{
  int e = blockIdx.x * 256 + threadIdx.x;
  if (e >= E + n) return;
  float ear[HID];
  if (e < E) {
    float ta[FE];
    #pragma unroll
    for (int k = 0; k < FE; k++) ta[k] = eattr[(size_t)e * FE + k];
    #pragma unroll
    for (int c = 0; c < HID; c++) {
      float acc = be[c];
      #pragma unroll
      for (int k = 0; k < FE; k++) acc += ta[k] * we[k * HID + c];
      ear[c] = fmaxf(acc, 0.f);
    }
  } else {
    const float* mrow = mean_ea + (size_t)(e - E) * HID;
    #pragma unroll
    for (int c = 0; c < HID; c++) ear[c] = mrow[c];
  }
  float a1[4] = {0, 0, 0, 0}, a2[4] = {0, 0, 0, 0};
  #pragma unroll
  for (int c = 0; c < HID; c++) {
    float ec = ear[c];
    #pragma unroll
    for (int hd = 0; hd < 4; hd++) {
      a1[hd] += ec * vE[c * 4 + hd];
      a2[hd] += ec * vE[256 + c * 4 + hd];
    }
  }
  #pragma unroll
  for (int hd = 0; hd < 4; hd++) {
    aeg1[(size_t)e * 4 + hd] = a1[hd];
    aeg2[(size_t)e * 4 + hd] = a2[hd];
  }
}

// h = x @ lin  [n,256]  + per-head att dots s_src, s_dst. 8 nodes per block.
__global__ __launch_bounds__(256) void k_h(const float* __restrict__ xin,
    const float* __restrict__ lin, const float* __restrict__ atts,
    const float* __restrict__ attd,
    float* __restrict__ h, float* __restrict__ ssrc, float* __restrict__ sdst, int n)
{
  int t = threadIdx.x; int w = t >> 6, lane = t & 63;
  int v0 = blockIdx.x * 8;
  __shared__ float xs[8][HID];
  for (int i = t; i < 8 * HID; i += 256) {
    int vv = v0 + (i >> 6);
    xs[i >> 6][i & 63] = (vv < n) ? xin[(size_t)vv * HID + (i & 63)] : 0.f;
  }
  __syncthreads();
  float acc[8];
  #pragma unroll
  for (int i = 0; i < 8; i++) acc[i] = 0.f;
  for (int k = 0; k < HID; k++) {
    float lv = lin[k * 256 + t];
    #pragma unroll
    for (int i = 0; i < 8; i++) acc[i] += xs[i][k] * lv;
  }
  float as_ = atts[w * 64 + lane], ad_ = attd[w * 64 + lane];
  #pragma unroll
  for (int i = 0; i < 8; i++) {
    int v = v0 + i;
    if (v < n) h[(size_t)v * 256 + t] = acc[i];
    float ps = acc[i] * as_, pd = acc[i] * ad_;
    #pragma unroll
    for (int off = 32; off; off >>= 1) {
      ps += __shfl_xor(ps, off);
      pd += __shfl_xor(pd, off);
    }
    if (lane == 0 && v < n) { ssrc[v * 4 + w] = ps; sdst[v * 4 + w] = pd; }
  }
}

// Fused per-destination-node: softmax over incoming edges (+self loop),
// alpha write-out, alpha-weighted aggregation of h[src], head-mean + bias
// + leaky_relu(0.01) + LayerNorm. One block (4 waves = 4 heads) per node.
__global__ __launch_bounds__(256) void k_node(
    const float* __restrict__ h, const float* __restrict__ ssrc,
    const float* __restrict__ sdst, const float* __restrict__ aeg,
    const int* __restrict__ rowptr, const int* __restrict__ eidArr,
    const int* __restrict__ srcA, const float* __restrict__ bias,
    const float* __restrict__ gamma, const float* __restrict__ beta,
    float* __restrict__ alpha_out, float* __restrict__ xout, int n, int E)
{
  int v = blockIdx.x;
  int t = threadIdx.x; int w = t >> 6, lane = t & 63;
  int r0 = rowptr[v], r1 = rowptr[v + 1];
  int deg = r1 - r0; int ne = deg + 1;  // + self loop (index E+v, src=v)
  float sd = sdst[v * 4 + w];

  // phase 1: max over edges (leaky_relu 0.2 applied)
  float m = -INFINITY;
  for (int j = lane; j < ne; j += 64) {
    int s, idx;
    if (j < deg) { int e = eidArr[r0 + j]; s = srcA[e]; idx = e; }
    else         { s = v; idx = E + v; }
    float a = ssrc[s * 4 + w] + sd + aeg[(size_t)idx * 4 + w];
    a = (a > 0.f) ? a : 0.2f * a;
    m = fmaxf(m, a);
  }
  #pragma unroll
  for (int off = 32; off; off >>= 1) m = fmaxf(m, __shfl_xor(m, off));

  // phase 2: denominator
  float den = 0.f;
  for (int j = lane; j < ne; j += 64) {
    int s, idx;
    if (j < deg) { int e = eidArr[r0 + j]; s = srcA[e]; idx = e; }
    else         { s = v; idx = E + v; }
    float a = ssrc[s * 4 + w] + sd + aeg[(size_t)idx * 4 + w];
    a = (a > 0.f) ? a : 0.2f * a;
    den += expf(a - m);
  }
  #pragma unroll
  for (int off = 32; off; off >>= 1) den += __shfl_xor(den, off);
  float rden = 1.f / den;

  // phase 3: write alpha
  for (int j = lane; j < ne; j += 64) {
    int s, idx;
    if (j < deg) { int e = eidArr[r0 + j]; s = srcA[e]; idx = e; }
    else         { s = v; idx = E + v; }
    float a = ssrc[s * 4 + w] + sd + aeg[(size_t)idx * 4 + w];
    a = (a > 0.f) ? a : 0.2f * a;
    alpha_out[(size_t)idx * 4 + w] = expf(a - m) * rden;
  }

  // phase 4: aggregate h[src] * alpha (serial over edges, parallel over channels)
  float acc = 0.f;
  for (int j = 0; j < ne; j++) {
    int s, idx;
    if (j < deg) { int e = eidArr[r0 + j]; s = srcA[e]; idx = e; }
    else         { s = v; idx = E + v; }
    float a = ssrc[s * 4 + w] + sd + aeg[(size_t)idx * 4 + w];
    a = (a > 0.f) ? a : 0.2f * a;
    float al = expf(a - m) * rden;
    acc += al * h[(size_t)s * 256 + t];
  }

  // epilogue: mean over heads + bias + leaky_relu(0.01) + LayerNorm(64)
  __shared__ float tmp[256];
  tmp[t] = acc;
  __syncthreads();
  if (w == 0) {
    float val = (tmp[lane] + tmp[64 + lane] + tmp[128 + lane] + tmp[192 + lane]) * 0.25f
              + bias[lane];
    val = (val > 0.f) ? val : 0.01f * val;
    float mu = val;
    #pragma unroll
    for (int off = 32; off; off >>= 1) mu += __shfl_xor(mu, off);
    mu *= (1.f / 64.f);
    float d = val - mu;
    float var = d * d;
    #pragma unroll
    for (int off = 32; off; off >>= 1) var += __shfl_xor(var, off);
    var *= (1.f / 64.f);
    float y = d * rsqrtf(var + 1e-5f) * gamma[lane] + beta[lane];
    xout[(size_t)v * HID + lane] = y;
  }
}

extern "C" void kernel_launch(void* const* d_in, const int* in_sizes, int n_in,
                              void* d_out, int out_size, void* d_ws, size_t ws_size,
                              hipStream_t stream)
{
  const float* x     = (const float*)d_in[0];
  const int*   eidx  = (const int*)d_in[1];
  const float* eattr = (const float*)d_in[2];
  const float* wn    = (const float*)d_in[3];
  const float* bn    = (const float*)d_in[4];
  const float* we    = (const float*)d_in[5];
  const float* be    = (const float*)d_in[6];
  const float* lin1  = (const float*)d_in[7];
  const float* line1 = (const float*)d_in[8];
  const float* as1   = (const float*)d_in[9];
  const float* ad1   = (const float*)d_in[10];
  const float* ae1   = (const float*)d_in[11];
  const float* b1    = (const float*)d_in[12];
  const float* g1    = (const float*)d_in[13];
  const float* bt1   = (const float*)d_in[14];
  const float* lin2  = (const float*)d_in[15];
  const float* line2 = (const float*)d_in[16];
  const float* as2   = (const float*)d_in[17];
  const float* ad2   = (const float*)d_in[18];
  const float* ae2   = (const float*)d_in[19];
  const float* b2    = (const float*)d_in[20];
  const float* g2    = (const float*)d_in[21];
  const float* bt2   = (const float*)d_in[22];

  int n = in_sizes[0] / FN;
  int E = in_sizes[1] / 2;
  const int* srcA = eidx;
  const int* dstA = eidx + E;

  float* out_h2 = (float*)d_out;
  float* alpha1 = out_h2 + (size_t)n * HID;
  float* alpha2 = alpha1 + (size_t)(E + n) * 4;

  char* ws = (char*)d_ws;
  size_t off = 0;
  auto alloc = [&](size_t bytes) -> char* {
    char* p = ws + off;
    off += (bytes + 255) & ~(size_t)255;
    return p;
  };
  float* x1      = (float*)alloc((size_t)n * HID * 4);
  float* h1      = (float*)alloc((size_t)n * HID * 4);
  float* h       = (float*)alloc((size_t)n * 256 * 4);
  float* mean_ea = (float*)alloc((size_t)n * HID * 4);
  float* aeg1    = (float*)alloc((size_t)(E + n) * 4 * 4);
  float* aeg2    = (float*)alloc((size_t)(E + n) * 4 * 4);
  float* ssrc    = (float*)alloc((size_t)n * 4 * 4);
  float* sdst    = (float*)alloc((size_t)n * 4 * 4);
  float* vE      = (float*)alloc(512 * 4);
  int*   deg     = (int*)alloc((size_t)n * 4);
  int*   cnt     = (int*)alloc((size_t)n * 4);
  int*   rowptr  = (int*)alloc((size_t)(n + 1) * 4);
  int*   eid     = (int*)alloc((size_t)E * 4);

  hipMemsetAsync(deg, 0, (size_t)n * 4, stream);
  hipMemsetAsync(cnt, 0, (size_t)n * 4, stream);

  k_x1<<<(n + 3) / 4, 256, 0, stream>>>(x, wn, bn, x1, n);
  k_deg<<<(E + 255) / 256, 256, 0, stream>>>(dstA, deg, E);
  k_scan<<<1, 1024, 0, stream>>>(deg, rowptr, n);
  k_fill<<<(E + 255) / 256, 256, 0, stream>>>(dstA, rowptr, cnt, eid, E);
  k_mean<<<(n + 3) / 4, 256, 0, stream>>>(eattr, we, be, rowptr, eid, mean_ea, n);
  k_vE<<<2, 256, 0, stream>>>(line1, ae1, line2, ae2, vE);
  k_aeg<<<(E + n + 255) / 256, 256, 0, stream>>>(eattr, we, be, mean_ea, vE, aeg1, aeg2, E, n);

  // layer 1
  k_h<<<(n + 7) / 8, 256, 0, stream>>>(x1, lin1, as1, ad1, h, ssrc, sdst, n);
  k_node<<<n, 256, 0, stream>>>(h, ssrc, sdst, aeg1, rowptr, eid, srcA,
                                b1, g1, bt1, alpha1, h1, n, E);
  // layer 2
  k_h<<<(n + 7) / 8, 256, 0, stream>>>(h1, lin2, as2, ad2, h, ssrc, sdst, n);
  k_node<<<n, 256, 0, stream>>>(h, ssrc, sdst, aeg2, rowptr, eid, srcA,
                                b2, g2, bt2, alpha2, out_h2, n, E);
}

// Round 2
// 471.273 us; speedup vs baseline: 1.5135x; 1.5135x over previous
//
#include <hip/hip_runtime.h>

#define FN 32
#define FE 16
#define HID 64
#define HEADS 4
#define CHC 64
// H*C = 256

// x1 = relu(x @ wn + bn), 4 nodes per 256-thread block
__global__ __launch_bounds__(256) void k_x1(const float* __restrict__ x,
    const float* __restrict__ wn, const float* __restrict__ bn,
    float* __restrict__ x1, int n)
{
  int t = threadIdx.x; int w = t >> 6; int lane = t & 63;
  int v = blockIdx.x * 4 + w;
  __shared__ float xs[4][FN];
  if (v < n && lane < FN) xs[w][lane] = x[(size_t)v * FN + lane];
  __syncthreads();
  if (v >= n) return;
  float acc = bn[lane];
  #pragma unroll
  for (int k = 0; k < FN; k++) acc += xs[w][k] * wn[k * HID + lane];
  x1[(size_t)v * HID + lane] = fmaxf(acc, 0.f);
}

__global__ __launch_bounds__(256) void k_deg(const int* __restrict__ dst,
                                             int* __restrict__ deg, int E)
{
  int e = blockIdx.x * 256 + threadIdx.x;
  if (e < E) atomicAdd(&deg[dst[e]], 1);
}

// exclusive prefix sum of deg -> rowptr[0..n], single block, shfl-scan
__global__ __launch_bounds__(1024) void k_scan(const int* __restrict__ deg,
                                               int* __restrict__ rowptr, int n)
{
  __shared__ int wsum[16];
  __shared__ int carry_s;
  int t = threadIdx.x, wv = t >> 6, lane = t & 63;
  if (t == 0) carry_s = 0;
  __syncthreads();
  for (int base = 0; base < n; base += 1024) {
    int i = base + t;
    int val = (i < n) ? deg[i] : 0;
    int sc = val;
    #pragma unroll
    for (int off = 1; off < 64; off <<= 1) {
      int u = __shfl_up(sc, off);
      if (lane >= off) sc += u;
    }
    if (lane == 63) wsum[wv] = sc;
    __syncthreads();
    int c0 = carry_s;
    int woff = 0;
    #pragma unroll
    for (int k = 0; k < 16; k++) woff += (k < wv) ? wsum[k] : 0;
    if (i < n) rowptr[i] = c0 + woff + sc - val;
    __syncthreads();
    if (t == 0) {
      int tot = 0;
      #pragma unroll
      for (int k = 0; k < 16; k++) tot += wsum[k];
      carry_s = c0 + tot;
    }
    __syncthreads();
  }
  if (t == 0) rowptr[n] = carry_s;
}

__global__ __launch_bounds__(256) void k_fill(const int* __restrict__ dst,
    const int* __restrict__ rowptr, int* __restrict__ cnt,
    int* __restrict__ eid, int E)
{
  int e = blockIdx.x * 256 + threadIdx.x;
  if (e < E) {
    int d = dst[e];
    int pos = rowptr[d] + atomicAdd(&cnt[d], 1);
    eid[pos] = e;
  }
}

// mean of relu(edge_attr @ we + be) over incoming edges per node
__global__ __launch_bounds__(256) void k_mean(const float* __restrict__ eattr,
    const float* __restrict__ we, const float* __restrict__ be,
    const int* __restrict__ rowptr, const int* __restrict__ eidArr,
    float* __restrict__ mean_ea, int n)
{
  int t = threadIdx.x; int w = t >> 6; int c = t & 63;
  int v = blockIdx.x * 4 + w;
  if (v >= n) return;
  float wreg[FE];
  #pragma unroll
  for (int k = 0; k < FE; k++) wreg[k] = we[k * HID + c];
  float breg = be[c];
  int r0 = rowptr[v], r1 = rowptr[v + 1];
  float s = 0.f;
  for (int j = r0; j < r1; j++) {
    int e = eidArr[j];
    const float4* er = (const float4*)(eattr + (size_t)e * FE);
    float4 A = er[0], B = er[1], C4 = er[2], D = er[3];
    float acc = breg;
    acc += A.x * wreg[0] + A.y * wreg[1] + A.z * wreg[2] + A.w * wreg[3];
    acc += B.x * wreg[4] + B.y * wreg[5] + B.z * wreg[6] + B.w * wreg[7];
    acc += C4.x * wreg[8] + C4.y * wreg[9] + C4.z * wreg[10] + C4.w * wreg[11];
    acc += D.x * wreg[12] + D.y * wreg[13] + D.z * wreg[14] + D.w * wreg[15];
    s += fmaxf(acc, 0.f);
  }
  mean_ea[(size_t)v * HID + c] = s / fmaxf((float)(r1 - r0), 1.f);
}

// vE[l][c][h] = sum_cc line_l[c][h*64+cc] * ae_l[h][cc]   (512 values total)
__global__ void k_vE(const float* __restrict__ line1, const float* __restrict__ ae1,
                     const float* __restrict__ line2, const float* __restrict__ ae2,
                     float* __restrict__ vE)
{
  int t = blockIdx.x * blockDim.x + threadIdx.x;
  if (t >= 512) return;
  int l = t >> 8; int c = (t >> 2) & 63; int hd = t & 3;
  const float* line = l ? line2 : line1;
  const float* ae   = l ? ae2 : ae1;
  float acc = 0.f;
  for (int cc = 0; cc < CHC; cc++)
    acc += line[c * (HEADS * CHC) + hd * CHC + cc] * ae[hd * CHC + cc];
  vE[t] = acc;
}

// reduce 8 per-lane values over 64 lanes (array-halving butterfly, 10 shfl),
// then store: entries 0..3 -> aeg1[e*4+h], 4..7 -> aeg2[e*4+h]
__device__ __forceinline__ void reduce8_store(const float p[8],
    float* __restrict__ aeg1, float* __restrict__ aeg2, size_t e, int lane, bool active)
{
  float q[4];
  {
    bool hi = lane & 1;
    #pragma unroll
    for (int m = 0; m < 4; m++) {
      float keep = hi ? p[m + 4] : p[m];
      float send = hi ? p[m] : p[m + 4];
      q[m] = keep + __shfl_xor(send, 1);
    }
  }
  float r[2];
  {
    bool hi = lane & 2;
    #pragma unroll
    for (int m = 0; m < 2; m++) {
      float keep = hi ? q[m + 2] : q[m];
      float send = hi ? q[m] : q[m + 2];
      r[m] = keep + __shfl_xor(send, 2);
    }
  }
  float s;
  {
    bool hi = lane & 4;
    float keep = hi ? r[1] : r[0];
    float send = hi ? r[0] : r[1];
    s = keep + __shfl_xor(send, 4);
  }
  s += __shfl_xor(s, 8);
  s += __shfl_xor(s, 16);
  s += __shfl_xor(s, 32);
  // lane i (i<8) holds entry ((i&1)<<2) | (i&2) | ((i>>2)&1)
  if (active && lane < 8) {
    int entry = ((lane & 1) << 2) | (lane & 2) | ((lane >> 2) & 1);
    if (entry < 4) aeg1[e * 4 + entry] = s;
    else           aeg2[e * 4 + entry - 4] = s;
  }
}

// a_edge for real edges: lane=c layout, weights in registers, eattr staged in LDS
__global__ __launch_bounds__(256) void k_aeg_e(const float* __restrict__ eattr,
    const float* __restrict__ we, const float* __restrict__ be,
    const float* __restrict__ vE,
    float* __restrict__ aeg1, float* __restrict__ aeg2, int E)
{
  __shared__ float ta_s[256][FE];   // 16 KB
  int t = threadIdx.x, wv = t >> 6, lane = t & 63;
  size_t e0 = (size_t)blockIdx.x * 256;
  // stage 256 edges x 16 floats, coalesced float4
  for (int i = t; i < 256 * FE / 4; i += 256) {
    size_t e = e0 + (i >> 2);
    float4 val = make_float4(0.f, 0.f, 0.f, 0.f);
    if (e < (size_t)E) val = ((const float4*)(eattr + e * FE))[i & 3];
    ((float4*)ta_s)[i] = val;
  }
  __syncthreads();

  float wreg[FE];
  #pragma unroll
  for (int k = 0; k < FE; k++) wreg[k] = we[k * HID + lane];
  float breg = be[lane];
  float v1r[4], v2r[4];
  #pragma unroll
  for (int h = 0; h < 4; h++) { v1r[h] = vE[lane * 4 + h]; v2r[h] = vE[256 + lane * 4 + h]; }

  for (int j = 0; j < 64; j++) {
    int le = wv * 64 + j;
    size_t e = e0 + le;
    if (e >= (size_t)E) break;
    const float4* tae = (const float4*)ta_s[le];
    float4 A = tae[0], B = tae[1], C4 = tae[2], D = tae[3];
    float ear = breg;
    ear += A.x * wreg[0] + A.y * wreg[1] + A.z * wreg[2] + A.w * wreg[3];
    ear += B.x * wreg[4] + B.y * wreg[5] + B.z * wreg[6] + B.w * wreg[7];
    ear += C4.x * wreg[8] + C4.y * wreg[9] + C4.z * wreg[10] + C4.w * wreg[11];
    ear += D.x * wreg[12] + D.y * wreg[13] + D.z * wreg[14] + D.w * wreg[15];
    ear = fmaxf(ear, 0.f);
    float p[8];
    #pragma unroll
    for (int h = 0; h < 4; h++) { p[h] = ear * v1r[h]; p[4 + h] = ear * v2r[h]; }
    reduce8_store(p, aeg1, aeg2, e, lane, true);
  }
}

// a_edge for self-loops: ear = mean_ea row; one node per wave
__global__ __launch_bounds__(256) void k_aeg_l(const float* __restrict__ mean_ea,
    const float* __restrict__ vE,
    float* __restrict__ aeg1, float* __restrict__ aeg2, int E, int n)
{
  int t = threadIdx.x, wv = t >> 6, lane = t & 63;
  int v = blockIdx.x * 4 + wv;
  if (v >= n) return;
  float ear = mean_ea[(size_t)v * HID + lane];
  float p[8];
  #pragma unroll
  for (int h = 0; h < 4; h++) {
    p[h] = ear * vE[lane * 4 + h];
    p[4 + h] = ear * vE[256 + lane * 4 + h];
  }
  reduce8_store(p, aeg1, aeg2, (size_t)E + v, lane, true);
}

// h = x @ lin  [n,256]  + per-head att dots s_src, s_dst. 8 nodes per block.
__global__ __launch_bounds__(256) void k_h(const float* __restrict__ xin,
    const float* __restrict__ lin, const float* __restrict__ atts,
    const float* __restrict__ attd,
    float* __restrict__ h, float* __restrict__ ssrc, float* __restrict__ sdst, int n)
{
  int t = threadIdx.x; int w = t >> 6, lane = t & 63;
  int v0 = blockIdx.x * 8;
  __shared__ float xs[8][HID];
  for (int i = t; i < 8 * HID; i += 256) {
    int vv = v0 + (i >> 6);
    xs[i >> 6][i & 63] = (vv < n) ? xin[(size_t)vv * HID + (i & 63)] : 0.f;
  }
  __syncthreads();
  float acc[8];
  #pragma unroll
  for (int i = 0; i < 8; i++) acc[i] = 0.f;
  for (int k = 0; k < HID; k++) {
    float lv = lin[k * 256 + t];
    #pragma unroll
    for (int i = 0; i < 8; i++) acc[i] += xs[i][k] * lv;
  }
  float as_ = atts[w * 64 + lane], ad_ = attd[w * 64 + lane];
  #pragma unroll
  for (int i = 0; i < 8; i++) {
    int v = v0 + i;
    if (v < n) h[(size_t)v * 256 + t] = acc[i];
    float ps = acc[i] * as_, pd = acc[i] * ad_;
    #pragma unroll
    for (int off = 32; off; off >>= 1) {
      ps += __shfl_xor(ps, off);
      pd += __shfl_xor(pd, off);
    }
    if (lane == 0 && v < n) { ssrc[v * 4 + w] = ps; sdst[v * 4 + w] = pd; }
  }
}

// Fused per-destination-node: softmax + alpha write + aggregation + head-mean
// + bias + leaky_relu(0.01) + LayerNorm. One block (4 waves = 4 heads) per node.
__global__ __launch_bounds__(256) void k_node(
    const float* __restrict__ h, const float* __restrict__ ssrc,
    const float* __restrict__ sdst, const float* __restrict__ aeg,
    const int* __restrict__ rowptr, const int* __restrict__ eidArr,
    const int* __restrict__ srcA, const float* __restrict__ bias,
    const float* __restrict__ gamma, const float* __restrict__ beta,
    float* __restrict__ alpha_out, float* __restrict__ xout, int n, int E)
{
  int v = blockIdx.x;
  int t = threadIdx.x; int w = t >> 6, lane = t & 63;
  int r0 = rowptr[v], r1 = rowptr[v + 1];
  int deg = r1 - r0; int ne = deg + 1;  // + self loop (index E+v, src=v)
  float sd = sdst[v * 4 + w];
  float acc = 0.f;

  if (ne <= 64) {
    // one lane per edge; lane==deg is the self-loop
    int s = v; size_t idx = (size_t)E + v;
    bool valid = (lane < ne);
    if (lane < deg) { int e = eidArr[r0 + lane]; s = srcA[e]; idx = e; }
    float a = -INFINITY;
    if (valid) {
      a = ssrc[s * 4 + w] + sd + aeg[idx * 4 + w];
      a = (a > 0.f) ? a : 0.2f * a;
    }
    float m = a;
    #pragma unroll
    for (int off = 32; off; off >>= 1) m = fmaxf(m, __shfl_xor(m, off));
    float ex = valid ? expf(a - m) : 0.f;
    float den = ex;
    #pragma unroll
    for (int off = 32; off; off >>= 1) den += __shfl_xor(den, off);
    float alpha = ex / den;
    if (valid) alpha_out[idx * 4 + w] = alpha;
    // aggregation: channel c = lane of head w
    for (int j = 0; j < ne; j++) {
      float al = __shfl(alpha, j);
      int sj = __shfl(s, j);
      acc += al * h[(size_t)sj * 256 + w * 64 + lane];
    }
  } else {
    // generic strided fallback (rare)
    float m = -INFINITY;
    for (int j = lane; j < ne; j += 64) {
      int s; size_t idx;
      if (j < deg) { int e = eidArr[r0 + j]; s = srcA[e]; idx = e; }
      else         { s = v; idx = (size_t)E + v; }
      float a = ssrc[s * 4 + w] + sd + aeg[idx * 4 + w];
      a = (a > 0.f) ? a : 0.2f * a;
      m = fmaxf(m, a);
    }
    #pragma unroll
    for (int off = 32; off; off >>= 1) m = fmaxf(m, __shfl_xor(m, off));
    float den = 0.f;
    for (int j = lane; j < ne; j += 64) {
      int s; size_t idx;
      if (j < deg) { int e = eidArr[r0 + j]; s = srcA[e]; idx = e; }
      else         { s = v; idx = (size_t)E + v; }
      float a = ssrc[s * 4 + w] + sd + aeg[idx * 4 + w];
      a = (a > 0.f) ? a : 0.2f * a;
      den += expf(a - m);
    }
    #pragma unroll
    for (int off = 32; off; off >>= 1) den += __shfl_xor(den, off);
    float rden = 1.f / den;
    for (int j = lane; j < ne; j += 64) {
      int s; size_t idx;
      if (j < deg) { int e = eidArr[r0 + j]; s = srcA[e]; idx = e; }
      else         { s = v; idx = (size_t)E + v; }
      float a = ssrc[s * 4 + w] + sd + aeg[idx * 4 + w];
      a = (a > 0.f) ? a : 0.2f * a;
      alpha_out[idx * 4 + w] = expf(a - m) * rden;
    }
    for (int j = 0; j < ne; j++) {
      int s; size_t idx;
      if (j < deg) { int e = eidArr[r0 + j]; s = srcA[e]; idx = e; }
      else         { s = v; idx = (size_t)E + v; }
      float a = ssrc[s * 4 + w] + sd + aeg[idx * 4 + w];
      a = (a > 0.f) ? a : 0.2f * a;
      float al = expf(a - m) * rden;
      acc += al * h[(size_t)s * 256 + t];
    }
  }

  // epilogue: mean over heads + bias + leaky_relu(0.01) + LayerNorm(64)
  __shared__ float tmp[256];
  tmp[t] = acc;
  __syncthreads();
  if (w == 0) {
    float val = (tmp[lane] + tmp[64 + lane] + tmp[128 + lane] + tmp[192 + lane]) * 0.25f
              + bias[lane];
    val = (val > 0.f) ? val : 0.01f * val;
    float mu = val;
    #pragma unroll
    for (int off = 32; off; off >>= 1) mu += __shfl_xor(mu, off);
    mu *= (1.f / 64.f);
    float d = val - mu;
    float var = d * d;
    #pragma unroll
    for (int off = 32; off; off >>= 1) var += __shfl_xor(var, off);
    var *= (1.f / 64.f);
    float y = d * rsqrtf(var + 1e-5f) * gamma[lane] + beta[lane];
    xout[(size_t)v * HID + lane] = y;
  }
}

extern "C" void kernel_launch(void* const* d_in, const int* in_sizes, int n_in,
                              void* d_out, int out_size, void* d_ws, size_t ws_size,
                              hipStream_t stream)
{
  const float* x     = (const float*)d_in[0];
  const int*   eidx  = (const int*)d_in[1];
  const float* eattr = (const float*)d_in[2];
  const float* wn    = (const float*)d_in[3];
  const float* bn    = (const float*)d_in[4];
  const float* we    = (const float*)d_in[5];
  const float* be    = (const float*)d_in[6];
  const float* lin1  = (const float*)d_in[7];
  const float* line1 = (const float*)d_in[8];
  const float* as1   = (const float*)d_in[9];
  const float* ad1   = (const float*)d_in[10];
  const float* ae1   = (const float*)d_in[11];
  const float* b1    = (const float*)d_in[12];
  const float* g1    = (const float*)d_in[13];
  const float* bt1   = (const float*)d_in[14];
  const float* lin2  = (const float*)d_in[15];
  const float* line2 = (const float*)d_in[16];
  const float* as2   = (const float*)d_in[17];
  const float* ad2   = (const float*)d_in[18];
  const float* ae2   = (const float*)d_in[19];
  const float* b2    = (const float*)d_in[20];
  const float* g2    = (const float*)d_in[21];
  const float* bt2   = (const float*)d_in[22];

  int n = in_sizes[0] / FN;
  int E = in_sizes[1] / 2;
  const int* srcA = eidx;
  const int* dstA = eidx + E;

  float* out_h2 = (float*)d_out;
  float* alpha1 = out_h2 + (size_t)n * HID;
  float* alpha2 = alpha1 + (size_t)(E + n) * 4;

  char* ws = (char*)d_ws;
  size_t off = 0;
  auto alloc = [&](size_t bytes) -> char* {
    char* p = ws + off;
    off += (bytes + 255) & ~(size_t)255;
    return p;
  };
  float* x1      = (float*)alloc((size_t)n * HID * 4);
  float* h1      = (float*)alloc((size_t)n * HID * 4);
  float* h       = (float*)alloc((size_t)n * 256 * 4);
  float* mean_ea = (float*)alloc((size_t)n * HID * 4);
  float* aeg1    = (float*)alloc((size_t)(E + n) * 4 * 4);
  float* aeg2    = (float*)alloc((size_t)(E + n) * 4 * 4);
  float* ssrc    = (float*)alloc((size_t)n * 4 * 4);
  float* sdst    = (float*)alloc((size_t)n * 4 * 4);
  float* vE      = (float*)alloc(512 * 4);
  int*   deg     = (int*)alloc((size_t)n * 4);
  int*   cnt     = (int*)alloc((size_t)n * 4);
  int*   rowptr  = (int*)alloc((size_t)(n + 1) * 4);
  int*   eid     = (int*)alloc((size_t)E * 4);

  hipMemsetAsync(deg, 0, (size_t)n * 4, stream);
  hipMemsetAsync(cnt, 0, (size_t)n * 4, stream);

  k_x1<<<(n + 3) / 4, 256, 0, stream>>>(x, wn, bn, x1, n);
  k_deg<<<(E + 255) / 256, 256, 0, stream>>>(dstA, deg, E);
  k_scan<<<1, 1024, 0, stream>>>(deg, rowptr, n);
  k_fill<<<(E + 255) / 256, 256, 0, stream>>>(dstA, rowptr, cnt, eid, E);
  k_mean<<<(n + 3) / 4, 256, 0, stream>>>(eattr, we, be, rowptr, eid, mean_ea, n);
  k_vE<<<2, 256, 0, stream>>>(line1, ae1, line2, ae2, vE);
  k_aeg_e<<<(E + 255) / 256, 256, 0, stream>>>(eattr, we, be, vE, aeg1, aeg2, E);
  k_aeg_l<<<(n + 3) / 4, 256, 0, stream>>>(mean_ea, vE, aeg1, aeg2, E, n);

  // layer 1
  k_h<<<(n + 7) / 8, 256, 0, stream>>>(x1, lin1, as1, ad1, h, ssrc, sdst, n);
  k_node<<<n, 256, 0, stream>>>(h, ssrc, sdst, aeg1, rowptr, eid, srcA,
                                b1, g1, bt1, alpha1, h1, n, E);
  // layer 2
  k_h<<<(n + 7) / 8, 256, 0, stream>>>(h1, lin2, as2, ad2, h, ssrc, sdst, n);
  k_node<<<n, 256, 0, stream>>>(h, ssrc, sdst, aeg2, rowptr, eid, srcA,
                                b2, g2, bt2, alpha2, out_h2, n, E);
}

// Round 3
// 366.945 us; speedup vs baseline: 1.9438x; 1.2843x over previous
//
#include <hip/hip_runtime.h>

#define FN 32
#define FE 16
#define HID 64
#define HEADS 4
#define CHC 64
// H*C = 256

__device__ __forceinline__ float bf2f(unsigned short u) {
  unsigned int x = ((unsigned int)u) << 16;
  return __builtin_bit_cast(float, x);
}
__device__ __forceinline__ unsigned short f2bf(float f) {
  unsigned int x = __builtin_bit_cast(unsigned int, f);
  unsigned int r = (x + 0x7fff + ((x >> 16) & 1)) >> 16;   // RNE
  return (unsigned short)r;
}

// x1 = relu(x @ wn + bn), 4 nodes per 256-thread block
__global__ __launch_bounds__(256) void k_x1(const float* __restrict__ x,
    const float* __restrict__ wn, const float* __restrict__ bn,
    float* __restrict__ x1, int n)
{
  int t = threadIdx.x; int w = t >> 6; int lane = t & 63;
  int v = blockIdx.x * 4 + w;
  __shared__ float xs[4][FN];
  if (v < n && lane < FN) xs[w][lane] = x[(size_t)v * FN + lane];
  __syncthreads();
  if (v >= n) return;
  float acc = bn[lane];
  #pragma unroll
  for (int k = 0; k < FN; k++) acc += xs[w][k] * wn[k * HID + lane];
  x1[(size_t)v * HID + lane] = fmaxf(acc, 0.f);
}

__global__ __launch_bounds__(256) void k_deg(const int* __restrict__ dst,
                                             int* __restrict__ deg, int E)
{
  int e = blockIdx.x * 256 + threadIdx.x;
  if (e < E) atomicAdd(&deg[dst[e]], 1);
}

// ---- 3-kernel exclusive scan of deg -> rowptr ----
__global__ __launch_bounds__(1024) void k_scan1(const int* __restrict__ deg,
    int* __restrict__ rowptr, int* __restrict__ bsum, int n)
{
  __shared__ int wsum[16];
  int t = threadIdx.x, wv = t >> 6, lane = t & 63;
  int i = blockIdx.x * 1024 + t;
  int val = (i < n) ? deg[i] : 0;
  int sc = val;
  #pragma unroll
  for (int off = 1; off < 64; off <<= 1) {
    int u = __shfl_up(sc, off);
    if (lane >= off) sc += u;
  }
  if (lane == 63) wsum[wv] = sc;
  __syncthreads();
  int woff = 0;
  #pragma unroll
  for (int k = 0; k < 16; k++) woff += (k < wv) ? wsum[k] : 0;
  if (i < n) rowptr[i] = woff + sc - val;
  if (t == 0) {
    int tot = 0;
    #pragma unroll
    for (int k = 0; k < 16; k++) tot += wsum[k];
    bsum[blockIdx.x] = tot;
  }
}

__global__ __launch_bounds__(1024) void k_scan2(const int* __restrict__ bsum,
    int* __restrict__ boff, int* __restrict__ rowptr, int nb, int n)
{
  __shared__ int wsum[16];
  int t = threadIdx.x, wv = t >> 6, lane = t & 63;
  int val = (t < nb) ? bsum[t] : 0;
  int sc = val;
  #pragma unroll
  for (int off = 1; off < 64; off <<= 1) {
    int u = __shfl_up(sc, off);
    if (lane >= off) sc += u;
  }
  if (lane == 63) wsum[wv] = sc;
  __syncthreads();
  int woff = 0;
  #pragma unroll
  for (int k = 0; k < 16; k++) woff += (k < wv) ? wsum[k] : 0;
  if (t < nb) boff[t] = woff + sc - val;
  if (t == 0) {
    int tot = 0;
    #pragma unroll
    for (int k = 0; k < 16; k++) tot += wsum[k];
    rowptr[n] = tot;
  }
}

__global__ __launch_bounds__(1024) void k_scan3(int* __restrict__ rowptr,
    const int* __restrict__ boff, int n)
{
  int i = blockIdx.x * 1024 + threadIdx.x;
  if (i < n) rowptr[i] += boff[blockIdx.x];
}

// CSR fill: eid (csr pos -> edge), srcs (csr pos -> src node), perm (edge -> csr pos)
__global__ __launch_bounds__(256) void k_fill(const int* __restrict__ src,
    const int* __restrict__ dst, const int* __restrict__ rowptr,
    int* __restrict__ cnt, int* __restrict__ eid, int* __restrict__ srcs,
    int* __restrict__ perm, int E)
{
  int e = blockIdx.x * 256 + threadIdx.x;
  if (e < E) {
    int d = dst[e];
    int pos = rowptr[d] + atomicAdd(&cnt[d], 1);
    eid[pos] = e;
    srcs[pos] = src[e];
    perm[e] = pos;
  }
}

// vE[l][c][h] = sum_cc line_l[c][h*64+cc] * ae_l[h][cc]   (512 values total)
__global__ void k_vE(const float* __restrict__ line1, const float* __restrict__ ae1,
                     const float* __restrict__ line2, const float* __restrict__ ae2,
                     float* __restrict__ vE)
{
  int t = blockIdx.x * blockDim.x + threadIdx.x;
  if (t >= 512) return;
  int l = t >> 8; int c = (t >> 2) & 63; int hd = t & 3;
  const float* line = l ? line2 : line1;
  const float* ae   = l ? ae2 : ae1;
  float acc = 0.f;
  for (int cc = 0; cc < CHC; cc++)
    acc += line[c * (HEADS * CHC) + hd * CHC + cc] * ae[hd * CHC + cc];
  vE[t] = acc;
}

// reduce 8 per-lane values over 64 lanes (array-halving butterfly, 10 shfl),
// then store entries 0..3 -> aeg1[pos*4+h], 4..7 -> aeg2[pos*4+h]
__device__ __forceinline__ void reduce8_store(const float p[8],
    float* __restrict__ aeg1, float* __restrict__ aeg2, size_t pos, int lane)
{
  float q[4];
  {
    bool hi = lane & 1;
    #pragma unroll
    for (int m = 0; m < 4; m++) {
      float keep = hi ? p[m + 4] : p[m];
      float send = hi ? p[m] : p[m + 4];
      q[m] = keep + __shfl_xor(send, 1);
    }
  }
  float r[2];
  {
    bool hi = lane & 2;
    #pragma unroll
    for (int m = 0; m < 2; m++) {
      float keep = hi ? q[m + 2] : q[m];
      float send = hi ? q[m] : q[m + 2];
      r[m] = keep + __shfl_xor(send, 2);
    }
  }
  float s;
  {
    bool hi = lane & 4;
    float keep = hi ? r[1] : r[0];
    float send = hi ? r[0] : r[1];
    s = keep + __shfl_xor(send, 4);
  }
  s += __shfl_xor(s, 8);
  s += __shfl_xor(s, 16);
  s += __shfl_xor(s, 32);
  if (lane < 8) {
    int entry = ((lane & 1) << 2) | (lane & 2) | ((lane >> 2) & 1);
    if (entry < 4) aeg1[pos * 4 + entry] = s;
    else           aeg2[pos * 4 + entry - 4] = s;
  }
}

// a_edge for real edges, written in CSR order via perm
__global__ __launch_bounds__(256) void k_aeg_e(const float* __restrict__ eattr,
    const float* __restrict__ we, const float* __restrict__ be,
    const float* __restrict__ vE, const int* __restrict__ perm,
    float* __restrict__ aeg1, float* __restrict__ aeg2, int E)
{
  __shared__ float ta_s[256][FE];   // 16 KB
  __shared__ int perm_s[256];
  int t = threadIdx.x, wv = t >> 6, lane = t & 63;
  size_t e0 = (size_t)blockIdx.x * 256;
  for (int i = t; i < 256 * FE / 4; i += 256) {
    size_t e = e0 + (i >> 2);
    float4 val = make_float4(0.f, 0.f, 0.f, 0.f);
    if (e < (size_t)E) val = ((const float4*)(eattr + e * FE))[i & 3];
    ((float4*)ta_s)[i] = val;
  }
  {
    size_t e = e0 + t;
    perm_s[t] = (e < (size_t)E) ? perm[e] : 0;
  }
  __syncthreads();

  float wreg[FE];
  #pragma unroll
  for (int k = 0; k < FE; k++) wreg[k] = we[k * HID + lane];
  float breg = be[lane];
  float v1r[4], v2r[4];
  #pragma unroll
  for (int h = 0; h < 4; h++) { v1r[h] = vE[lane * 4 + h]; v2r[h] = vE[256 + lane * 4 + h]; }

  for (int j = 0; j < 64; j++) {
    int le = wv * 64 + j;
    size_t e = e0 + le;
    if (e >= (size_t)E) break;
    const float4* tae = (const float4*)ta_s[le];
    float4 A = tae[0], B = tae[1], C4 = tae[2], D = tae[3];
    float ear = breg;
    ear += A.x * wreg[0] + A.y * wreg[1] + A.z * wreg[2] + A.w * wreg[3];
    ear += B.x * wreg[4] + B.y * wreg[5] + B.z * wreg[6] + B.w * wreg[7];
    ear += C4.x * wreg[8] + C4.y * wreg[9] + C4.z * wreg[10] + C4.w * wreg[11];
    ear += D.x * wreg[12] + D.y * wreg[13] + D.z * wreg[14] + D.w * wreg[15];
    ear = fmaxf(ear, 0.f);
    float p[8];
    #pragma unroll
    for (int h = 0; h < 4; h++) { p[h] = ear * v1r[h]; p[4 + h] = ear * v2r[h]; }
    reduce8_store(p, aeg1, aeg2, (size_t)perm_s[le], lane);
  }
}

// self-loop a_edge: mean of relu(ea) over incoming edges, then dot with vE.
// One node per wave; slot E+v (identity position).
__global__ __launch_bounds__(256) void k_mean_aeg(const float* __restrict__ eattr,
    const float* __restrict__ we, const float* __restrict__ be,
    const int* __restrict__ rowptr, const int* __restrict__ eidArr,
    const float* __restrict__ vE,
    float* __restrict__ aeg1, float* __restrict__ aeg2, int E, int n)
{
  int t = threadIdx.x; int wv = t >> 6; int c = t & 63;
  int v = blockIdx.x * 4 + wv;
  if (v >= n) return;
  float wreg[FE];
  #pragma unroll
  for (int k = 0; k < FE; k++) wreg[k] = we[k * HID + c];
  float breg = be[c];
  int r0 = rowptr[v], r1 = rowptr[v + 1];
  float s = 0.f;
  for (int j = r0; j < r1; j++) {
    int e = eidArr[j];
    const float4* er = (const float4*)(eattr + (size_t)e * FE);
    float4 A = er[0], B = er[1], C4 = er[2], D = er[3];
    float acc = breg;
    acc += A.x * wreg[0] + A.y * wreg[1] + A.z * wreg[2] + A.w * wreg[3];
    acc += B.x * wreg[4] + B.y * wreg[5] + B.z * wreg[6] + B.w * wreg[7];
    acc += C4.x * wreg[8] + C4.y * wreg[9] + C4.z * wreg[10] + C4.w * wreg[11];
    acc += D.x * wreg[12] + D.y * wreg[13] + D.z * wreg[14] + D.w * wreg[15];
    s += fmaxf(acc, 0.f);
  }
  float ear = s / fmaxf((float)(r1 - r0), 1.f);
  float p[8];
  #pragma unroll
  for (int h = 0; h < 4; h++) {
    p[h] = ear * vE[c * 4 + h];
    p[4 + h] = ear * vE[256 + c * 4 + h];
  }
  reduce8_store(p, aeg1, aeg2, (size_t)E + v, c);
}

// h(bf16) = x @ lin  [n,256]  + per-head att dots s_src, s_dst. 16 nodes/block.
#define NPB 16
__global__ __launch_bounds__(256) void k_h(const float* __restrict__ xin,
    const float* __restrict__ lin, const float* __restrict__ atts,
    const float* __restrict__ attd,
    unsigned short* __restrict__ h_bf, float* __restrict__ ssrc,
    float* __restrict__ sdst, int n)
{
  int t = threadIdx.x; int w = t >> 6, lane = t & 63;
  int v0 = blockIdx.x * NPB;
  __shared__ float xs[NPB][HID];
  for (int i = t; i < NPB * HID; i += 256) {
    int vv = v0 + (i >> 6);
    xs[i >> 6][i & 63] = (vv < n) ? xin[(size_t)vv * HID + (i & 63)] : 0.f;
  }
  __syncthreads();
  float acc[NPB];
  #pragma unroll
  for (int i = 0; i < NPB; i++) acc[i] = 0.f;
  for (int k = 0; k < HID; k++) {
    float lv = lin[k * 256 + t];
    #pragma unroll
    for (int i = 0; i < NPB; i++) acc[i] += xs[i][k] * lv;
  }
  float as_ = atts[w * 64 + lane], ad_ = attd[w * 64 + lane];
  #pragma unroll
  for (int i = 0; i < NPB; i++) {
    int v = v0 + i;
    if (v < n) h_bf[(size_t)v * 256 + t] = f2bf(acc[i]);
    float ps = acc[i] * as_, pd = acc[i] * ad_;
    #pragma unroll
    for (int off = 32; off; off >>= 1) {
      ps += __shfl_xor(ps, off);
      pd += __shfl_xor(pd, off);
    }
    if (lane == 0 && v < n) { ssrc[v * 4 + w] = ps; sdst[v * 4 + w] = pd; }
  }
}

// Fused per-destination-node: softmax + alpha write + aggregation + head-mean
// + bias + leaky_relu(0.01) + LayerNorm. One block per node.
__global__ __launch_bounds__(256) void k_node(
    const unsigned short* __restrict__ h_bf, const float* __restrict__ ssrc,
    const float* __restrict__ sdst, const float* __restrict__ aegc,
    const int* __restrict__ rowptr, const int* __restrict__ eidArr,
    const int* __restrict__ srcs, const float* __restrict__ bias,
    const float* __restrict__ gamma, const float* __restrict__ beta,
    float* __restrict__ alpha_out, float* __restrict__ xout, int n, int E)
{
  int v = blockIdx.x;
  int t = threadIdx.x; int w = t >> 6, lane = t & 63;
  __shared__ float alpha_s[64 * 5];   // stride-5 pad: conflict-free
  __shared__ int svec[64];
  __shared__ float part[256];
  int r0 = rowptr[v], r1 = rowptr[v + 1];
  int deg = r1 - r0; int ne = deg + 1;  // + self loop
  float sd = sdst[v * 4 + w];

  if (ne <= 64) {
    // ---- phase A: softmax, lane = edge j, wave = head w ----
    int s = v; int eo = E + v;
    bool valid = (lane < ne);
    if (lane < deg) { s = srcs[r0 + lane]; eo = eidArr[r0 + lane]; }
    float a = -INFINITY;
    if (valid) {
      float ae = (lane < deg) ? aegc[(size_t)(r0 + lane) * 4 + w]
                              : aegc[((size_t)E + v) * 4 + w];
      a = ssrc[s * 4 + w] + sd + ae;
      a = (a > 0.f) ? a : 0.2f * a;
    }
    float m = a;
    #pragma unroll
    for (int off = 32; off; off >>= 1) m = fmaxf(m, __shfl_xor(m, off));
    float ex = valid ? __expf(a - m) : 0.f;
    float den = ex;
    #pragma unroll
    for (int off = 32; off; off >>= 1) den += __shfl_xor(den, off);
    float alpha = ex / den;
    if (valid) {
      alpha_out[(size_t)eo * 4 + w] = alpha;
      alpha_s[lane * 5 + w] = alpha;
      if (w == 0) svec[lane] = s;
    }
    __syncthreads();
    // ---- phase B: aggregation, wave = edge (strided), uint2 = 4 bf16/lane ----
    int head = lane >> 4;
    int coff = lane * 4;   // channel block [4][64] flattened: head=coff>>6
    float a0 = 0.f, a1 = 0.f, a2 = 0.f, a3 = 0.f;
    for (int j = w; j < ne; j += 4) {
      int sj = svec[j];
      float al = alpha_s[j * 5 + head];
      uint2 u = *(const uint2*)(h_bf + (size_t)sj * 256 + coff);
      a0 += al * bf2f((unsigned short)(u.x & 0xffff));
      a1 += al * bf2f((unsigned short)(u.x >> 16));
      a2 += al * bf2f((unsigned short)(u.y & 0xffff));
      a3 += al * bf2f((unsigned short)(u.y >> 16));
    }
    // reduce over heads (lane bits 4,5)
    a0 += __shfl_xor(a0, 16); a0 += __shfl_xor(a0, 32);
    a1 += __shfl_xor(a1, 16); a1 += __shfl_xor(a1, 32);
    a2 += __shfl_xor(a2, 16); a2 += __shfl_xor(a2, 32);
    a3 += __shfl_xor(a3, 16); a3 += __shfl_xor(a3, 32);
    if (lane < 16) {
      float4 val = make_float4(a0, a1, a2, a3);
      *(float4*)(&part[w * 64 + lane * 4]) = val;   // head-summed partial per wave
    }
  } else {
    // ---- generic fallback (deg > 63) ----
    float m = -INFINITY;
    for (int j = lane; j < ne; j += 64) {
      int s; size_t ap;
      if (j < deg) { s = srcs[r0 + j]; ap = (size_t)(r0 + j); }
      else         { s = v; ap = (size_t)E + v; }
      float a = ssrc[s * 4 + w] + sd + aegc[ap * 4 + w];
      a = (a > 0.f) ? a : 0.2f * a;
      m = fmaxf(m, a);
    }
    #pragma unroll
    for (int off = 32; off; off >>= 1) m = fmaxf(m, __shfl_xor(m, off));
    float den = 0.f;
    for (int j = lane; j < ne; j += 64) {
      int s; size_t ap;
      if (j < deg) { s = srcs[r0 + j]; ap = (size_t)(r0 + j); }
      else         { s = v; ap = (size_t)E + v; }
      float a = ssrc[s * 4 + w] + sd + aegc[ap * 4 + w];
      a = (a > 0.f) ? a : 0.2f * a;
      den += __expf(a - m);
    }
    #pragma unroll
    for (int off = 32; off; off >>= 1) den += __shfl_xor(den, off);
    float rden = 1.f / den;
    for (int j = lane; j < ne; j += 64) {
      int s; size_t ap, eo;
      if (j < deg) { s = srcs[r0 + j]; ap = (size_t)(r0 + j); eo = eidArr[r0 + j]; }
      else         { s = v; ap = (size_t)E + v; eo = (size_t)E + v; }
      float a = ssrc[s * 4 + w] + sd + aegc[ap * 4 + w];
      a = (a > 0.f) ? a : 0.2f * a;
      alpha_out[eo * 4 + w] = __expf(a - m) * rden;
    }
    float acc = 0.f;
    for (int j = 0; j < ne; j++) {
      int s; size_t ap;
      if (j < deg) { s = srcs[r0 + j]; ap = (size_t)(r0 + j); }
      else         { s = v; ap = (size_t)E + v; }
      float a = ssrc[s * 4 + w] + sd + aegc[ap * 4 + w];
      a = (a > 0.f) ? a : 0.2f * a;
      float al = __expf(a - m) * rden;
      acc += al * bf2f(h_bf[(size_t)s * 256 + t]);
    }
    part[t] = acc;
  }
  __syncthreads();
  // epilogue: mean over heads(waves) + bias + leaky_relu(0.01) + LayerNorm(64)
  if (w == 0) {
    float val = (part[lane] + part[64 + lane] + part[128 + lane] + part[192 + lane]) * 0.25f
              + bias[lane];
    val = (val > 0.f) ? val : 0.01f * val;
    float mu = val;
    #pragma unroll
    for (int off = 32; off; off >>= 1) mu += __shfl_xor(mu, off);
    mu *= (1.f / 64.f);
    float d = val - mu;
    float var = d * d;
    #pragma unroll
    for (int off = 32; off; off >>= 1) var += __shfl_xor(var, off);
    var *= (1.f / 64.f);
    float y = d * rsqrtf(var + 1e-5f) * gamma[lane] + beta[lane];
    xout[(size_t)v * HID + lane] = y;
  }
}

extern "C" void kernel_launch(void* const* d_in, const int* in_sizes, int n_in,
                              void* d_out, int out_size, void* d_ws, size_t ws_size,
                              hipStream_t stream)
{
  const float* x     = (const float*)d_in[0];
  const int*   eidx  = (const int*)d_in[1];
  const float* eattr = (const float*)d_in[2];
  const float* wn    = (const float*)d_in[3];
  const float* bn    = (const float*)d_in[4];
  const float* we    = (const float*)d_in[5];
  const float* be    = (const float*)d_in[6];
  const float* lin1  = (const float*)d_in[7];
  const float* line1 = (const float*)d_in[8];
  const float* as1   = (const float*)d_in[9];
  const float* ad1   = (const float*)d_in[10];
  const float* ae1   = (const float*)d_in[11];
  const float* b1    = (const float*)d_in[12];
  const float* g1    = (const float*)d_in[13];
  const float* bt1   = (const float*)d_in[14];
  const float* lin2  = (const float*)d_in[15];
  const float* line2 = (const float*)d_in[16];
  const float* as2   = (const float*)d_in[17];
  const float* ad2   = (const float*)d_in[18];
  const float* ae2   = (const float*)d_in[19];
  const float* b2    = (const float*)d_in[20];
  const float* g2    = (const float*)d_in[21];
  const float* bt2   = (const float*)d_in[22];

  int n = in_sizes[0] / FN;
  int E = in_sizes[1] / 2;
  const int* srcA = eidx;
  const int* dstA = eidx + E;

  float* out_h2 = (float*)d_out;
  float* alpha1 = out_h2 + (size_t)n * HID;
  float* alpha2 = alpha1 + (size_t)(E + n) * 4;

  char* ws = (char*)d_ws;
  size_t off = 0;
  auto alloc = [&](size_t bytes) -> char* {
    char* p = ws + off;
    off += (bytes + 255) & ~(size_t)255;
    return p;
  };
  unsigned short* h_bf = (unsigned short*)alloc((size_t)n * 256 * 2);
  float* x1      = (float*)alloc((size_t)n * HID * 4);
  float* h1      = (float*)alloc((size_t)n * HID * 4);
  float* aeg1c   = (float*)alloc((size_t)(E + n) * 4 * 4);
  float* aeg2c   = (float*)alloc((size_t)(E + n) * 4 * 4);
  float* ssrc    = (float*)alloc((size_t)n * 4 * 4);
  float* sdst    = (float*)alloc((size_t)n * 4 * 4);
  float* vE      = (float*)alloc(512 * 4);
  int*   deg     = (int*)alloc((size_t)n * 4);
  int*   cnt     = (int*)alloc((size_t)n * 4);
  int*   rowptr  = (int*)alloc((size_t)(n + 1) * 4);
  int*   eid     = (int*)alloc((size_t)E * 4);
  int*   srcs    = (int*)alloc((size_t)E * 4);
  int*   perm    = (int*)alloc((size_t)E * 4);
  int*   bsum    = (int*)alloc(1024 * 4);
  int*   boff    = (int*)alloc(1024 * 4);

  hipMemsetAsync(deg, 0, (size_t)n * 4, stream);
  hipMemsetAsync(cnt, 0, (size_t)n * 4, stream);

  int nb = (n + 1023) / 1024;
  k_x1<<<(n + 3) / 4, 256, 0, stream>>>(x, wn, bn, x1, n);
  k_deg<<<(E + 255) / 256, 256, 0, stream>>>(dstA, deg, E);
  k_scan1<<<nb, 1024, 0, stream>>>(deg, rowptr, bsum, n);
  k_scan2<<<1, 1024, 0, stream>>>(bsum, boff, rowptr, nb, n);
  k_scan3<<<nb, 1024, 0, stream>>>(rowptr, boff, n);
  k_fill<<<(E + 255) / 256, 256, 0, stream>>>(srcA, dstA, rowptr, cnt, eid, srcs, perm, E);
  k_vE<<<2, 256, 0, stream>>>(line1, ae1, line2, ae2, vE);
  k_aeg_e<<<(E + 255) / 256, 256, 0, stream>>>(eattr, we, be, vE, perm, aeg1c, aeg2c, E);
  k_mean_aeg<<<(n + 3) / 4, 256, 0, stream>>>(eattr, we, be, rowptr, eid, vE, aeg1c, aeg2c, E, n);

  // layer 1
  k_h<<<(n + NPB - 1) / NPB, 256, 0, stream>>>(x1, lin1, as1, ad1, h_bf, ssrc, sdst, n);
  k_node<<<n, 256, 0, stream>>>(h_bf, ssrc, sdst, aeg1c, rowptr, eid, srcs,
                                b1, g1, bt1, alpha1, h1, n, E);
  // layer 2
  k_h<<<(n + NPB - 1) / NPB, 256, 0, stream>>>(h1, lin2, as2, ad2, h_bf, ssrc, sdst, n);
  k_node<<<n, 256, 0, stream>>>(h_bf, ssrc, sdst, aeg2c, rowptr, eid, srcs,
                                b2, g2, bt2, alpha2, out_h2, n, E);
}

// Round 4
// 295.680 us; speedup vs baseline: 2.4122x; 1.2410x over previous
//
#include <hip/hip_runtime.h>

#define FN 32
#define FE 16
#define HID 64
#define HEADS 4
#define CHC 64
// H*C = 256

__device__ __forceinline__ float bf2f(unsigned short u) {
  unsigned int x = ((unsigned int)u) << 16;
  return __builtin_bit_cast(float, x);
}
__device__ __forceinline__ unsigned short f2bf(float f) {
  unsigned int x = __builtin_bit_cast(unsigned int, f);
  unsigned int r = (x + 0x7fff + ((x >> 16) & 1)) >> 16;   // RNE
  return (unsigned short)r;
}

// x1 = relu(x @ wn + bn), 4 nodes per 256-thread block
__global__ __launch_bounds__(256) void k_x1(const float* __restrict__ x,
    const float* __restrict__ wn, const float* __restrict__ bn,
    float* __restrict__ x1, int n)
{
  int t = threadIdx.x; int w = t >> 6; int lane = t & 63;
  int v = blockIdx.x * 4 + w;
  __shared__ float xs[4][FN];
  if (v < n && lane < FN) xs[w][lane] = x[(size_t)v * FN + lane];
  __syncthreads();
  if (v >= n) return;
  float acc = bn[lane];
  #pragma unroll
  for (int k = 0; k < FN; k++) acc += xs[w][k] * wn[k * HID + lane];
  x1[(size_t)v * HID + lane] = fmaxf(acc, 0.f);
}

__global__ __launch_bounds__(256) void k_deg(const int* __restrict__ dst,
                                             int* __restrict__ deg, int E)
{
  int e = blockIdx.x * 256 + threadIdx.x;
  if (e < E) atomicAdd(&deg[dst[e]], 1);
}

// ---- 3-kernel exclusive scan of deg -> rowptr ----
__global__ __launch_bounds__(1024) void k_scan1(const int* __restrict__ deg,
    int* __restrict__ rowptr, int* __restrict__ bsum, int n)
{
  __shared__ int wsum[16];
  int t = threadIdx.x, wv = t >> 6, lane = t & 63;
  int i = blockIdx.x * 1024 + t;
  int val = (i < n) ? deg[i] : 0;
  int sc = val;
  #pragma unroll
  for (int off = 1; off < 64; off <<= 1) {
    int u = __shfl_up(sc, off);
    if (lane >= off) sc += u;
  }
  if (lane == 63) wsum[wv] = sc;
  __syncthreads();
  int woff = 0;
  #pragma unroll
  for (int k = 0; k < 16; k++) woff += (k < wv) ? wsum[k] : 0;
  if (i < n) rowptr[i] = woff + sc - val;
  if (t == 0) {
    int tot = 0;
    #pragma unroll
    for (int k = 0; k < 16; k++) tot += wsum[k];
    bsum[blockIdx.x] = tot;
  }
}

__global__ __launch_bounds__(1024) void k_scan2(const int* __restrict__ bsum,
    int* __restrict__ boff, int* __restrict__ rowptr, int nb, int n)
{
  __shared__ int wsum[16];
  int t = threadIdx.x, wv = t >> 6, lane = t & 63;
  int val = (t < nb) ? bsum[t] : 0;
  int sc = val;
  #pragma unroll
  for (int off = 1; off < 64; off <<= 1) {
    int u = __shfl_up(sc, off);
    if (lane >= off) sc += u;
  }
  if (lane == 63) wsum[wv] = sc;
  __syncthreads();
  int woff = 0;
  #pragma unroll
  for (int k = 0; k < 16; k++) woff += (k < wv) ? wsum[k] : 0;
  if (t < nb) boff[t] = woff + sc - val;
  if (t == 0) {
    int tot = 0;
    #pragma unroll
    for (int k = 0; k < 16; k++) tot += wsum[k];
    rowptr[n] = tot;
  }
}

__global__ __launch_bounds__(1024) void k_scan3(int* __restrict__ rowptr,
    const int* __restrict__ boff, int n)
{
  int i = blockIdx.x * 1024 + threadIdx.x;
  if (i < n) rowptr[i] += boff[blockIdx.x];
}

// CSR fill: eid (csr pos -> edge), srcs (csr pos -> src node), perm (edge -> csr pos)
__global__ __launch_bounds__(256) void k_fill(const int* __restrict__ src,
    const int* __restrict__ dst, const int* __restrict__ rowptr,
    int* __restrict__ cnt, int* __restrict__ eid, int* __restrict__ srcs,
    int* __restrict__ perm, int E)
{
  int e = blockIdx.x * 256 + threadIdx.x;
  if (e < E) {
    int d = dst[e];
    int pos = rowptr[d] + atomicAdd(&cnt[d], 1);
    eid[pos] = e;
    srcs[pos] = src[e];
    perm[e] = pos;
  }
}

// vE[l][c][h] = sum_cc line_l[c][h*64+cc] * ae_l[h][cc]   (512 values total)
__global__ void k_vE(const float* __restrict__ line1, const float* __restrict__ ae1,
                     const float* __restrict__ line2, const float* __restrict__ ae2,
                     float* __restrict__ vE)
{
  int t = blockIdx.x * blockDim.x + threadIdx.x;
  if (t >= 512) return;
  int l = t >> 8; int c = (t >> 2) & 63; int hd = t & 3;
  const float* line = l ? line2 : line1;
  const float* ae   = l ? ae2 : ae1;
  float acc = 0.f;
  for (int cc = 0; cc < CHC; cc++)
    acc += line[c * (HEADS * CHC) + hd * CHC + cc] * ae[hd * CHC + cc];
  vE[t] = acc;
}

// a_edge for real edges, lane-owns-edge, weights broadcast from LDS.
// Writes float4 per edge into CSR position perm[e] for both layers.
__global__ __launch_bounds__(256) void k_aeg_e(const float* __restrict__ eattr,
    const float* __restrict__ we, const float* __restrict__ be,
    const float* __restrict__ vE, const int* __restrict__ perm,
    float* __restrict__ aeg1, float* __restrict__ aeg2, int E)
{
  __shared__ float4 we_t4[HID][4];   // we^T: [c][k/4], 4 KB
  __shared__ float4 vE_s[2][HID];    // [layer][c] -> 4 heads, 2 KB
  __shared__ float  be_s[HID];
  int t = threadIdx.x;
  for (int i = t; i < FE * HID; i += 256) {
    int k = i >> 6, c = i & 63;
    ((float*)we_t4)[c * 16 + k] = we[i];
  }
  for (int i = t; i < 512; i += 256) ((float*)vE_s)[i] = vE[i];
  if (t < HID) be_s[t] = be[t];
  __syncthreads();

  int e = blockIdx.x * 256 + t;
  if (e >= E) return;
  const float4* er = (const float4*)(eattr + (size_t)e * FE);
  float4 A = er[0], B = er[1], C4 = er[2], D = er[3];
  float ta[FE] = {A.x, A.y, A.z, A.w, B.x, B.y, B.z, B.w,
                  C4.x, C4.y, C4.z, C4.w, D.x, D.y, D.z, D.w};
  float4 acc1 = make_float4(0.f, 0.f, 0.f, 0.f);
  float4 acc2 = make_float4(0.f, 0.f, 0.f, 0.f);
  #pragma unroll 4
  for (int c = 0; c < HID; c++) {
    float4 w0 = we_t4[c][0], w1 = we_t4[c][1], w2 = we_t4[c][2], w3 = we_t4[c][3];
    float ea = be_s[c];
    ea += ta[0] * w0.x + ta[1] * w0.y + ta[2] * w0.z + ta[3] * w0.w;
    ea += ta[4] * w1.x + ta[5] * w1.y + ta[6] * w1.z + ta[7] * w1.w;
    ea += ta[8] * w2.x + ta[9] * w2.y + ta[10] * w2.z + ta[11] * w2.w;
    ea += ta[12] * w3.x + ta[13] * w3.y + ta[14] * w3.z + ta[15] * w3.w;
    ea = fmaxf(ea, 0.f);
    float4 u1 = vE_s[0][c], u2 = vE_s[1][c];
    acc1.x += ea * u1.x; acc1.y += ea * u1.y; acc1.z += ea * u1.z; acc1.w += ea * u1.w;
    acc2.x += ea * u2.x; acc2.y += ea * u2.y; acc2.z += ea * u2.z; acc2.w += ea * u2.w;
  }
  int pos = perm[e];
  *(float4*)(aeg1 + (size_t)pos * 4) = acc1;
  *(float4*)(aeg2 + (size_t)pos * 4) = acc2;
}

// self-loop a_edge = mean over incoming edges of their aeg (relu precedes the
// mean, and the vE dot is linear). Segment-mean over CSR range, slot E+v.
__global__ __launch_bounds__(256) void k_self_aeg(const int* __restrict__ rowptr,
    float* __restrict__ aeg1, float* __restrict__ aeg2, int E, int n)
{
  int t = threadIdx.x;
  int v = blockIdx.x * 32 + (t >> 3);
  if (v >= n) return;
  int ent = t & 7;
  int h = ent & 3;
  const float* srcp = (ent < 4) ? aeg1 : aeg2;
  int r0 = rowptr[v], r1 = rowptr[v + 1];
  float s = 0.f;
  for (int j = r0; j < r1; j++) s += srcp[(size_t)j * 4 + h];
  float m = s / fmaxf((float)(r1 - r0), 1.f);
  if (ent < 4) aeg1[((size_t)E + v) * 4 + h] = m;
  else         aeg2[((size_t)E + v) * 4 + h] = m;
}

// h(bf16) = x @ lin  [n,256]  + per-head att dots s_src, s_dst. 16 nodes/block.
#define NPB 16
__global__ __launch_bounds__(256) void k_h(const float* __restrict__ xin,
    const float* __restrict__ lin, const float* __restrict__ atts,
    const float* __restrict__ attd,
    unsigned short* __restrict__ h_bf, float* __restrict__ ssrc,
    float* __restrict__ sdst, int n)
{
  int t = threadIdx.x; int w = t >> 6, lane = t & 63;
  int v0 = blockIdx.x * NPB;
  __shared__ float xs[NPB][HID];
  for (int i = t; i < NPB * HID; i += 256) {
    int vv = v0 + (i >> 6);
    xs[i >> 6][i & 63] = (vv < n) ? xin[(size_t)vv * HID + (i & 63)] : 0.f;
  }
  __syncthreads();
  float acc[NPB];
  #pragma unroll
  for (int i = 0; i < NPB; i++) acc[i] = 0.f;
  for (int k = 0; k < HID; k++) {
    float lv = lin[k * 256 + t];
    #pragma unroll
    for (int i = 0; i < NPB; i++) acc[i] += xs[i][k] * lv;
  }
  float as_ = atts[w * 64 + lane], ad_ = attd[w * 64 + lane];
  #pragma unroll
  for (int i = 0; i < NPB; i++) {
    int v = v0 + i;
    if (v < n) h_bf[(size_t)v * 256 + t] = f2bf(acc[i]);
    float ps = acc[i] * as_, pd = acc[i] * ad_;
    #pragma unroll
    for (int off = 32; off; off >>= 1) {
      ps += __shfl_xor(ps, off);
      pd += __shfl_xor(pd, off);
    }
    if (lane == 0 && v < n) { ssrc[v * 4 + w] = ps; sdst[v * 4 + w] = pd; }
  }
}

// Fused per-destination-node: softmax + alpha write + aggregation + head-mean
// + bias + leaky_relu(0.01) + LayerNorm. One block per node.
__global__ __launch_bounds__(256) void k_node(
    const unsigned short* __restrict__ h_bf, const float* __restrict__ ssrc,
    const float* __restrict__ sdst, const float* __restrict__ aegc,
    const int* __restrict__ rowptr, const int* __restrict__ eidArr,
    const int* __restrict__ srcs, const float* __restrict__ bias,
    const float* __restrict__ gamma, const float* __restrict__ beta,
    float* __restrict__ alpha_out, float* __restrict__ xout, int n, int E)
{
  int v = blockIdx.x;
  int t = threadIdx.x; int w = t >> 6, lane = t & 63;
  __shared__ float alpha_s[64 * 5];   // stride-5 pad: conflict-free
  __shared__ int svec[64];
  __shared__ float part[256];
  int r0 = rowptr[v], r1 = rowptr[v + 1];
  int deg = r1 - r0; int ne = deg + 1;  // + self loop
  float sd = sdst[v * 4 + w];

  if (ne <= 64) {
    // ---- phase A: softmax, lane = edge j, wave = head w ----
    int s = v; int eo = E + v;
    bool valid = (lane < ne);
    if (lane < deg) { s = srcs[r0 + lane]; eo = eidArr[r0 + lane]; }
    float a = -INFINITY;
    if (valid) {
      float ae = (lane < deg) ? aegc[(size_t)(r0 + lane) * 4 + w]
                              : aegc[((size_t)E + v) * 4 + w];
      a = ssrc[s * 4 + w] + sd + ae;
      a = (a > 0.f) ? a : 0.2f * a;
    }
    float m = a;
    #pragma unroll
    for (int off = 32; off; off >>= 1) m = fmaxf(m, __shfl_xor(m, off));
    float ex = valid ? __expf(a - m) : 0.f;
    float den = ex;
    #pragma unroll
    for (int off = 32; off; off >>= 1) den += __shfl_xor(den, off);
    float alpha = ex / den;
    if (valid) {
      alpha_out[(size_t)eo * 4 + w] = alpha;
      alpha_s[lane * 5 + w] = alpha;
      if (w == 0) svec[lane] = s;
    }
    __syncthreads();
    // ---- phase B: aggregation, wave = edge (strided), uint2 = 4 bf16/lane ----
    int head = lane >> 4;
    int coff = lane * 4;   // channel block [4][64] flattened: head=coff>>6
    float a0 = 0.f, a1 = 0.f, a2 = 0.f, a3 = 0.f;
    for (int j = w; j < ne; j += 4) {
      int sj = svec[j];
      float al = alpha_s[j * 5 + head];
      uint2 u = *(const uint2*)(h_bf + (size_t)sj * 256 + coff);
      a0 += al * bf2f((unsigned short)(u.x & 0xffff));
      a1 += al * bf2f((unsigned short)(u.x >> 16));
      a2 += al * bf2f((unsigned short)(u.y & 0xffff));
      a3 += al * bf2f((unsigned short)(u.y >> 16));
    }
    // reduce over heads (lane bits 4,5)
    a0 += __shfl_xor(a0, 16); a0 += __shfl_xor(a0, 32);
    a1 += __shfl_xor(a1, 16); a1 += __shfl_xor(a1, 32);
    a2 += __shfl_xor(a2, 16); a2 += __shfl_xor(a2, 32);
    a3 += __shfl_xor(a3, 16); a3 += __shfl_xor(a3, 32);
    if (lane < 16) {
      float4 val = make_float4(a0, a1, a2, a3);
      *(float4*)(&part[w * 64 + lane * 4]) = val;   // head-summed partial per wave
    }
  } else {
    // ---- generic fallback (deg > 63) ----
    float m = -INFINITY;
    for (int j = lane; j < ne; j += 64) {
      int s; size_t ap;
      if (j < deg) { s = srcs[r0 + j]; ap = (size_t)(r0 + j); }
      else         { s = v; ap = (size_t)E + v; }
      float a = ssrc[s * 4 + w] + sd + aegc[ap * 4 + w];
      a = (a > 0.f) ? a : 0.2f * a;
      m = fmaxf(m, a);
    }
    #pragma unroll
    for (int off = 32; off; off >>= 1) m = fmaxf(m, __shfl_xor(m, off));
    float den = 0.f;
    for (int j = lane; j < ne; j += 64) {
      int s; size_t ap;
      if (j < deg) { s = srcs[r0 + j]; ap = (size_t)(r0 + j); }
      else         { s = v; ap = (size_t)E + v; }
      float a = ssrc[s * 4 + w] + sd + aegc[ap * 4 + w];
      a = (a > 0.f) ? a : 0.2f * a;
      den += __expf(a - m);
    }
    #pragma unroll
    for (int off = 32; off; off >>= 1) den += __shfl_xor(den, off);
    float rden = 1.f / den;
    for (int j = lane; j < ne; j += 64) {
      int s; size_t ap, eo;
      if (j < deg) { s = srcs[r0 + j]; ap = (size_t)(r0 + j); eo = eidArr[r0 + j]; }
      else         { s = v; ap = (size_t)E + v; eo = (size_t)E + v; }
      float a = ssrc[s * 4 + w] + sd + aegc[ap * 4 + w];
      a = (a > 0.f) ? a : 0.2f * a;
      alpha_out[eo * 4 + w] = __expf(a - m) * rden;
    }
    float acc = 0.f;
    for (int j = 0; j < ne; j++) {
      int s; size_t ap;
      if (j < deg) { s = srcs[r0 + j]; ap = (size_t)(r0 + j); }
      else         { s = v; ap = (size_t)E + v; }
      float a = ssrc[s * 4 + w] + sd + aegc[ap * 4 + w];
      a = (a > 0.f) ? a : 0.2f * a;
      float al = __expf(a - m) * rden;
      acc += al * bf2f(h_bf[(size_t)s * 256 + t]);
    }
    part[t] = acc;
  }
  __syncthreads();
  // epilogue: mean over heads(waves) + bias + leaky_relu(0.01) + LayerNorm(64)
  if (w == 0) {
    float val = (part[lane] + part[64 + lane] + part[128 + lane] + part[192 + lane]) * 0.25f
              + bias[lane];
    val = (val > 0.f) ? val : 0.01f * val;
    float mu = val;
    #pragma unroll
    for (int off = 32; off; off >>= 1) mu += __shfl_xor(mu, off);
    mu *= (1.f / 64.f);
    float d = val - mu;
    float var = d * d;
    #pragma unroll
    for (int off = 32; off; off >>= 1) var += __shfl_xor(var, off);
    var *= (1.f / 64.f);
    float y = d * rsqrtf(var + 1e-5f) * gamma[lane] + beta[lane];
    xout[(size_t)v * HID + lane] = y;
  }
}

extern "C" void kernel_launch(void* const* d_in, const int* in_sizes, int n_in,
                              void* d_out, int out_size, void* d_ws, size_t ws_size,
                              hipStream_t stream)
{
  const float* x     = (const float*)d_in[0];
  const int*   eidx  = (const int*)d_in[1];
  const float* eattr = (const float*)d_in[2];
  const float* wn    = (const float*)d_in[3];
  const float* bn    = (const float*)d_in[4];
  const float* we    = (const float*)d_in[5];
  const float* be    = (const float*)d_in[6];
  const float* lin1  = (const float*)d_in[7];
  const float* line1 = (const float*)d_in[8];
  const float* as1   = (const float*)d_in[9];
  const float* ad1   = (const float*)d_in[10];
  const float* ae1   = (const float*)d_in[11];
  const float* b1    = (const float*)d_in[12];
  const float* g1    = (const float*)d_in[13];
  const float* bt1   = (const float*)d_in[14];
  const float* lin2  = (const float*)d_in[15];
  const float* line2 = (const float*)d_in[16];
  const float* as2   = (const float*)d_in[17];
  const float* ad2   = (const float*)d_in[18];
  const float* ae2   = (const float*)d_in[19];
  const float* b2    = (const float*)d_in[20];
  const float* g2    = (const float*)d_in[21];
  const float* bt2   = (const float*)d_in[22];

  int n = in_sizes[0] / FN;
  int E = in_sizes[1] / 2;
  const int* srcA = eidx;
  const int* dstA = eidx + E;

  float* out_h2 = (float*)d_out;
  float* alpha1 = out_h2 + (size_t)n * HID;
  float* alpha2 = alpha1 + (size_t)(E + n) * 4;

  char* ws = (char*)d_ws;
  size_t off = 0;
  auto alloc = [&](size_t bytes) -> char* {
    char* p = ws + off;
    off += (bytes + 255) & ~(size_t)255;
    return p;
  };
  unsigned short* h_bf = (unsigned short*)alloc((size_t)n * 256 * 2);
  float* x1      = (float*)alloc((size_t)n * HID * 4);
  float* h1      = (float*)alloc((size_t)n * HID * 4);
  float* aeg1c   = (float*)alloc((size_t)(E + n) * 4 * 4);
  float* aeg2c   = (float*)alloc((size_t)(E + n) * 4 * 4);
  float* ssrc    = (float*)alloc((size_t)n * 4 * 4);
  float* sdst    = (float*)alloc((size_t)n * 4 * 4);
  float* vE      = (float*)alloc(512 * 4);
  int*   deg     = (int*)alloc((size_t)n * 4);
  int*   cnt     = (int*)alloc((size_t)n * 4);
  int*   rowptr  = (int*)alloc((size_t)(n + 1) * 4);
  int*   eid     = (int*)alloc((size_t)E * 4);
  int*   srcs    = (int*)alloc((size_t)E * 4);
  int*   perm    = (int*)alloc((size_t)E * 4);
  int*   bsum    = (int*)alloc(1024 * 4);
  int*   boff    = (int*)alloc(1024 * 4);

  hipMemsetAsync(deg, 0, (size_t)n * 4, stream);
  hipMemsetAsync(cnt, 0, (size_t)n * 4, stream);

  int nb = (n + 1023) / 1024;
  k_x1<<<(n + 3) / 4, 256, 0, stream>>>(x, wn, bn, x1, n);
  k_deg<<<(E + 255) / 256, 256, 0, stream>>>(dstA, deg, E);
  k_scan1<<<nb, 1024, 0, stream>>>(deg, rowptr, bsum, n);
  k_scan2<<<1, 1024, 0, stream>>>(bsum, boff, rowptr, nb, n);
  k_scan3<<<nb, 1024, 0, stream>>>(rowptr, boff, n);
  k_fill<<<(E + 255) / 256, 256, 0, stream>>>(srcA, dstA, rowptr, cnt, eid, srcs, perm, E);
  k_vE<<<2, 256, 0, stream>>>(line1, ae1, line2, ae2, vE);
  k_aeg_e<<<(E + 255) / 256, 256, 0, stream>>>(eattr, we, be, vE, perm, aeg1c, aeg2c, E);
  k_self_aeg<<<(n + 31) / 32, 256, 0, stream>>>(rowptr, aeg1c, aeg2c, E, n);

  // layer 1
  k_h<<<(n + NPB - 1) / NPB, 256, 0, stream>>>(x1, lin1, as1, ad1, h_bf, ssrc, sdst, n);
  k_node<<<n, 256, 0, stream>>>(h_bf, ssrc, sdst, aeg1c, rowptr, eid, srcs,
                                b1, g1, bt1, alpha1, h1, n, E);
  // layer 2
  k_h<<<(n + NPB - 1) / NPB, 256, 0, stream>>>(h1, lin2, as2, ad2, h_bf, ssrc, sdst, n);
  k_node<<<n, 256, 0, stream>>>(h_bf, ssrc, sdst, aeg2c, rowptr, eid, srcs,
                                b2, g2, bt2, alpha2, out_h2, n, E);
}

// Round 5
// 252.616 us; speedup vs baseline: 2.8235x; 1.1705x over previous
//
#include <hip/hip_runtime.h>

#define FN 32
#define FE 16
#define HID 64
#define HEADS 4
#define CHC 64
// H*C = 256

__device__ __forceinline__ float bf2f(unsigned short u) {
  unsigned int x = ((unsigned int)u) << 16;
  return __builtin_bit_cast(float, x);
}
__device__ __forceinline__ unsigned short f2bf(float f) {
  unsigned int x = __builtin_bit_cast(unsigned int, f);
  unsigned int r = (x + 0x7fff + ((x >> 16) & 1)) >> 16;   // RNE
  return (unsigned short)r;
}

// reduce 8 per-lane values over 64 lanes (array-halving butterfly, 10 shfl),
// then store entries 0..3 -> arr1[pos*4+h], 4..7 -> arr2[pos*4+h]
__device__ __forceinline__ void reduce8_store(const float p[8],
    float* __restrict__ arr1, float* __restrict__ arr2, size_t pos, int lane)
{
  float q[4];
  {
    bool hi = lane & 1;
    #pragma unroll
    for (int m = 0; m < 4; m++) {
      float keep = hi ? p[m + 4] : p[m];
      float send = hi ? p[m] : p[m + 4];
      q[m] = keep + __shfl_xor(send, 1);
    }
  }
  float r[2];
  {
    bool hi = lane & 2;
    #pragma unroll
    for (int m = 0; m < 2; m++) {
      float keep = hi ? q[m + 2] : q[m];
      float send = hi ? q[m] : q[m + 2];
      r[m] = keep + __shfl_xor(send, 2);
    }
  }
  float s;
  {
    bool hi = lane & 4;
    float keep = hi ? r[1] : r[0];
    float send = hi ? r[0] : r[1];
    s = keep + __shfl_xor(send, 4);
  }
  s += __shfl_xor(s, 8);
  s += __shfl_xor(s, 16);
  s += __shfl_xor(s, 32);
  if (lane < 8) {
    int entry = ((lane & 1) << 2) | (lane & 2) | ((lane >> 2) & 1);
    if (entry < 4) arr1[pos * 4 + entry] = s;
    else           arr2[pos * 4 + entry - 4] = s;
  }
}

// vS/vD/vE[l][c][h]: folded attention vectors. 6 blocks: (layer, kind)
__global__ __launch_bounds__(256) void k_vecs(
    const float* __restrict__ lin1, const float* __restrict__ line1,
    const float* __restrict__ as1, const float* __restrict__ ad1,
    const float* __restrict__ ae1,
    const float* __restrict__ lin2, const float* __restrict__ line2,
    const float* __restrict__ as2, const float* __restrict__ ad2,
    const float* __restrict__ ae2,
    float* __restrict__ vS, float* __restrict__ vD, float* __restrict__ vE)
{
  int bi = blockIdx.x;         // 0..5
  int l = bi / 3, kind = bi % 3;
  const float* lin = (kind == 2) ? (l ? line2 : line1) : (l ? lin2 : lin1);
  const float* att = (kind == 0) ? (l ? as2 : as1)
                   : (kind == 1) ? (l ? ad2 : ad1) : (l ? ae2 : ae1);
  float* out = ((kind == 0) ? vS : (kind == 1) ? vD : vE) + l * 256;
  int t = threadIdx.x;
  int c = t >> 2, hd = t & 3;
  float acc = 0.f;
  for (int cc = 0; cc < CHC; cc++)
    acc += lin[c * (HEADS * CHC) + hd * CHC + cc] * att[hd * CHC + cc];
  out[c * 4 + hd] = acc;
}

// x1 = relu(x @ wn + bn) + layer-1 att dots (x1 . vS1 / vD1)
__global__ __launch_bounds__(256) void k_x1(const float* __restrict__ x,
    const float* __restrict__ wn, const float* __restrict__ bn,
    const float* __restrict__ vS, const float* __restrict__ vD,
    float* __restrict__ x1, float* __restrict__ ssrc, float* __restrict__ sdst,
    int n)
{
  int t = threadIdx.x; int w = t >> 6; int lane = t & 63;
  int v = blockIdx.x * 4 + w;
  __shared__ float xs[4][FN];
  if (v < n && lane < FN) xs[w][lane] = x[(size_t)v * FN + lane];
  __syncthreads();
  if (v >= n) return;
  float acc = bn[lane];
  #pragma unroll
  for (int k = 0; k < FN; k++) acc += xs[w][k] * wn[k * HID + lane];
  acc = fmaxf(acc, 0.f);
  x1[(size_t)v * HID + lane] = acc;
  float4 s4 = ((const float4*)vS)[lane];
  float4 d4 = ((const float4*)vD)[lane];
  float p[8] = {acc * s4.x, acc * s4.y, acc * s4.z, acc * s4.w,
                acc * d4.x, acc * d4.y, acc * d4.z, acc * d4.w};
  reduce8_store(p, ssrc, sdst, (size_t)v, lane);
}

// layer-2 att dots from h1
__global__ __launch_bounds__(256) void k_sdots(const float* __restrict__ xin,
    const float* __restrict__ vS, const float* __restrict__ vD,
    float* __restrict__ ssrc, float* __restrict__ sdst, int n)
{
  int t = threadIdx.x; int w = t >> 6; int lane = t & 63;
  int v = blockIdx.x * 4 + w;
  if (v >= n) return;
  float xc = xin[(size_t)v * HID + lane];
  float4 s4 = ((const float4*)vS)[lane];
  float4 d4 = ((const float4*)vD)[lane];
  float p[8] = {xc * s4.x, xc * s4.y, xc * s4.z, xc * s4.w,
                xc * d4.x, xc * d4.y, xc * d4.z, xc * d4.w};
  reduce8_store(p, ssrc, sdst, (size_t)v, lane);
}

__global__ __launch_bounds__(256) void k_deg(const int* __restrict__ dst,
                                             int* __restrict__ deg, int E)
{
  int e = blockIdx.x * 256 + threadIdx.x;
  if (e < E) atomicAdd(&deg[dst[e]], 1);
}

// ---- 3-kernel exclusive scan of deg -> rowptr ----
__global__ __launch_bounds__(1024) void k_scan1(const int* __restrict__ deg,
    int* __restrict__ rowptr, int* __restrict__ bsum, int n)
{
  __shared__ int wsum[16];
  int t = threadIdx.x, wv = t >> 6, lane = t & 63;
  int i = blockIdx.x * 1024 + t;
  int val = (i < n) ? deg[i] : 0;
  int sc = val;
  #pragma unroll
  for (int off = 1; off < 64; off <<= 1) {
    int u = __shfl_up(sc, off);
    if (lane >= off) sc += u;
  }
  if (lane == 63) wsum[wv] = sc;
  __syncthreads();
  int woff = 0;
  #pragma unroll
  for (int k = 0; k < 16; k++) woff += (k < wv) ? wsum[k] : 0;
  if (i < n) rowptr[i] = woff + sc - val;
  if (t == 0) {
    int tot = 0;
    #pragma unroll
    for (int k = 0; k < 16; k++) tot += wsum[k];
    bsum[blockIdx.x] = tot;
  }
}

__global__ __launch_bounds__(1024) void k_scan2(const int* __restrict__ bsum,
    int* __restrict__ boff, int* __restrict__ rowptr, int nb, int n)
{
  __shared__ int wsum[16];
  int t = threadIdx.x, wv = t >> 6, lane = t & 63;
  int val = (t < nb) ? bsum[t] : 0;
  int sc = val;
  #pragma unroll
  for (int off = 1; off < 64; off <<= 1) {
    int u = __shfl_up(sc, off);
    if (lane >= off) sc += u;
  }
  if (lane == 63) wsum[wv] = sc;
  __syncthreads();
  int woff = 0;
  #pragma unroll
  for (int k = 0; k < 16; k++) woff += (k < wv) ? wsum[k] : 0;
  if (t < nb) boff[t] = woff + sc - val;
  if (t == 0) {
    int tot = 0;
    #pragma unroll
    for (int k = 0; k < 16; k++) tot += wsum[k];
    rowptr[n] = tot;
  }
}

__global__ __launch_bounds__(1024) void k_scan3(int* __restrict__ rowptr,
    const int* __restrict__ boff, int n)
{
  int i = blockIdx.x * 1024 + threadIdx.x;
  if (i < n) rowptr[i] += boff[blockIdx.x];
}

// CSR fill
__global__ __launch_bounds__(256) void k_fill(const int* __restrict__ src,
    const int* __restrict__ dst, const int* __restrict__ rowptr,
    int* __restrict__ cnt, int* __restrict__ eid, int* __restrict__ srcs,
    int* __restrict__ perm, int E)
{
  int e = blockIdx.x * 256 + threadIdx.x;
  if (e < E) {
    int d = dst[e];
    int pos = rowptr[d] + atomicAdd(&cnt[d], 1);
    eid[pos] = e;
    srcs[pos] = src[e];
    perm[e] = pos;
  }
}

// a_edge for real edges, lane-owns-edge, weights broadcast from LDS.
__global__ __launch_bounds__(256) void k_aeg_e(const float* __restrict__ eattr,
    const float* __restrict__ we, const float* __restrict__ be,
    const float* __restrict__ vE, const int* __restrict__ perm,
    float* __restrict__ aeg1, float* __restrict__ aeg2, int E)
{
  __shared__ float4 we_t4[HID][4];
  __shared__ float4 vE_s[2][HID];
  __shared__ float  be_s[HID];
  int t = threadIdx.x;
  for (int i = t; i < FE * HID; i += 256) {
    int k = i >> 6, c = i & 63;
    ((float*)we_t4)[c * 16 + k] = we[i];
  }
  for (int i = t; i < 512; i += 256) ((float*)vE_s)[i] = vE[i];
  if (t < HID) be_s[t] = be[t];
  __syncthreads();

  int e = blockIdx.x * 256 + t;
  if (e >= E) return;
  const float4* er = (const float4*)(eattr + (size_t)e * FE);
  float4 A = er[0], B = er[1], C4 = er[2], D = er[3];
  float ta[FE] = {A.x, A.y, A.z, A.w, B.x, B.y, B.z, B.w,
                  C4.x, C4.y, C4.z, C4.w, D.x, D.y, D.z, D.w};
  float4 acc1 = make_float4(0.f, 0.f, 0.f, 0.f);
  float4 acc2 = make_float4(0.f, 0.f, 0.f, 0.f);
  #pragma unroll 4
  for (int c = 0; c < HID; c++) {
    float4 w0 = we_t4[c][0], w1 = we_t4[c][1], w2 = we_t4[c][2], w3 = we_t4[c][3];
    float ea = be_s[c];
    ea += ta[0] * w0.x + ta[1] * w0.y + ta[2] * w0.z + ta[3] * w0.w;
    ea += ta[4] * w1.x + ta[5] * w1.y + ta[6] * w1.z + ta[7] * w1.w;
    ea += ta[8] * w2.x + ta[9] * w2.y + ta[10] * w2.z + ta[11] * w2.w;
    ea += ta[12] * w3.x + ta[13] * w3.y + ta[14] * w3.z + ta[15] * w3.w;
    ea = fmaxf(ea, 0.f);
    float4 u1 = vE_s[0][c], u2 = vE_s[1][c];
    acc1.x += ea * u1.x; acc1.y += ea * u1.y; acc1.z += ea * u1.z; acc1.w += ea * u1.w;
    acc2.x += ea * u2.x; acc2.y += ea * u2.y; acc2.z += ea * u2.z; acc2.w += ea * u2.w;
  }
  int pos = perm[e];
  *(float4*)(aeg1 + (size_t)pos * 4) = acc1;
  *(float4*)(aeg2 + (size_t)pos * 4) = acc2;
}

// self-loop a_edge = segment-mean of CSR aeg values
__global__ __launch_bounds__(256) void k_self_aeg(const int* __restrict__ rowptr,
    float* __restrict__ aeg1, float* __restrict__ aeg2, int E, int n)
{
  int t = threadIdx.x;
  int v = blockIdx.x * 32 + (t >> 3);
  if (v >= n) return;
  int ent = t & 7;
  int h = ent & 3;
  const float* srcp = (ent < 4) ? aeg1 : aeg2;
  int r0 = rowptr[v], r1 = rowptr[v + 1];
  float s = 0.f;
  for (int j = r0; j < r1; j++) s += srcp[(size_t)j * 4 + h];
  float m = s / fmaxf((float)(r1 - r0), 1.f);
  if (ent < 4) aeg1[((size_t)E + v) * 4 + h] = m;
  else         aeg2[((size_t)E + v) * 4 + h] = m;
}

// h(bf16) = x @ lin  [n,256], 16 nodes/block. Pure GEMM.
#define NPB 16
__global__ __launch_bounds__(256) void k_h(const float* __restrict__ xin,
    const float* __restrict__ lin, unsigned short* __restrict__ h_bf, int n)
{
  int t = threadIdx.x;
  int v0 = blockIdx.x * NPB;
  __shared__ float xs[NPB][HID];
  for (int i = t; i < NPB * HID; i += 256) {
    int vv = v0 + (i >> 6);
    xs[i >> 6][i & 63] = (vv < n) ? xin[(size_t)vv * HID + (i & 63)] : 0.f;
  }
  __syncthreads();
  float acc[NPB];
  #pragma unroll
  for (int i = 0; i < NPB; i++) acc[i] = 0.f;
  for (int k = 0; k < HID; k++) {
    float lv = lin[k * 256 + t];
    #pragma unroll
    for (int i = 0; i < NPB; i++) acc[i] += xs[i][k] * lv;
  }
  #pragma unroll
  for (int i = 0; i < NPB; i++) {
    int v = v0 + i;
    if (v < n) h_bf[(size_t)v * 256 + t] = f2bf(acc[i]);
  }
}

// Fused per-node: softmax + alpha + aggregation + head-mean + bias + leaky +
// LayerNorm. WAVE per node, 4 nodes per 256-thread block, no LDS/sync.
__global__ __launch_bounds__(256) void k_node(
    const unsigned short* __restrict__ h_bf, const float* __restrict__ ssrc,
    const float* __restrict__ sdst, const float* __restrict__ aegc,
    const int* __restrict__ rowptr, const int* __restrict__ eidArr,
    const int* __restrict__ srcs, const float* __restrict__ bias,
    const float* __restrict__ gamma, const float* __restrict__ beta,
    float* __restrict__ alpha_out, float* __restrict__ xout, int n, int E)
{
  int t = threadIdx.x; int wv = t >> 6, lane = t & 63;
  int v = blockIdx.x * 4 + wv;
  if (v >= n) return;
  int r0 = rowptr[v], r1 = rowptr[v + 1];
  int deg = r1 - r0, ne = deg + 1;      // + self loop (edge id E+v, src v)
  int j = lane >> 2, h = lane & 3;      // softmax layout: 16 edge slots x 4 heads
  int coff = lane * 4;                  // aggregation: 4 channels per lane
  int hh = lane >> 4;                   // head owning those channels
  float sd = sdst[v * 4 + h];
  float acc0 = 0.f, acc1 = 0.f, acc2 = 0.f, acc3 = 0.f;

  if (ne <= 16) {
    // ---- single-pass softmax ----
    int s = v, eo = E + v;
    bool valid = (j < ne);
    if (j < deg) { s = srcs[r0 + j]; eo = eidArr[r0 + j]; }
    float a = -INFINITY;
    if (valid) {
      float ae = (j < deg) ? aegc[(size_t)(r0 + j) * 4 + h]
                           : aegc[((size_t)E + v) * 4 + h];
      a = ssrc[s * 4 + h] + sd + ae;
      a = (a > 0.f) ? a : 0.2f * a;
    }
    float m = a;
    m = fmaxf(m, __shfl_xor(m, 4));
    m = fmaxf(m, __shfl_xor(m, 8));
    m = fmaxf(m, __shfl_xor(m, 16));
    m = fmaxf(m, __shfl_xor(m, 32));
    float ex = valid ? __expf(a - m) : 0.f;
    float den = ex;
    den += __shfl_xor(den, 4);
    den += __shfl_xor(den, 8);
    den += __shfl_xor(den, 16);
    den += __shfl_xor(den, 32);
    float alpha = ex / den;
    if (valid) alpha_out[(size_t)eo * 4 + h] = alpha;
    // ---- aggregation: alpha/src via shfl, 2 loads in flight ----
    int jj = 0;
    for (; jj + 1 < ne; jj += 2) {
      int s0 = __shfl(s, jj * 4);
      int s1 = __shfl(s, jj * 4 + 4);
      float al0 = __shfl(alpha, jj * 4 + hh);
      float al1 = __shfl(alpha, jj * 4 + 4 + hh);
      uint2 u0 = *(const uint2*)(h_bf + (size_t)s0 * 256 + coff);
      uint2 u1 = *(const uint2*)(h_bf + (size_t)s1 * 256 + coff);
      acc0 += al0 * bf2f((unsigned short)(u0.x & 0xffff))
            + al1 * bf2f((unsigned short)(u1.x & 0xffff));
      acc1 += al0 * bf2f((unsigned short)(u0.x >> 16))
            + al1 * bf2f((unsigned short)(u1.x >> 16));
      acc2 += al0 * bf2f((unsigned short)(u0.y & 0xffff))
            + al1 * bf2f((unsigned short)(u1.y & 0xffff));
      acc3 += al0 * bf2f((unsigned short)(u0.y >> 16))
            + al1 * bf2f((unsigned short)(u1.y >> 16));
    }
    if (jj < ne) {
      int s0 = __shfl(s, jj * 4);
      float al0 = __shfl(alpha, jj * 4 + hh);
      uint2 u0 = *(const uint2*)(h_bf + (size_t)s0 * 256 + coff);
      acc0 += al0 * bf2f((unsigned short)(u0.x & 0xffff));
      acc1 += al0 * bf2f((unsigned short)(u0.x >> 16));
      acc2 += al0 * bf2f((unsigned short)(u0.y & 0xffff));
      acc3 += al0 * bf2f((unsigned short)(u0.y >> 16));
    }
  } else {
    // ---- chunked two-pass fallback (deg > 15) ----
    float m = -INFINITY;
    for (int jb = 0; jb < ne; jb += 16) {
      int jc = jb + j;
      if (jc < ne) {
        int s2 = (jc < deg) ? srcs[r0 + jc] : v;
        float ae = (jc < deg) ? aegc[(size_t)(r0 + jc) * 4 + h]
                              : aegc[((size_t)E + v) * 4 + h];
        float a = ssrc[s2 * 4 + h] + sd + ae;
        a = (a > 0.f) ? a : 0.2f * a;
        m = fmaxf(m, a);
      }
    }
    m = fmaxf(m, __shfl_xor(m, 4));
    m = fmaxf(m, __shfl_xor(m, 8));
    m = fmaxf(m, __shfl_xor(m, 16));
    m = fmaxf(m, __shfl_xor(m, 32));
    float den = 0.f;
    for (int jb = 0; jb < ne; jb += 16) {
      int jc = jb + j;
      if (jc < ne) {
        int s2 = (jc < deg) ? srcs[r0 + jc] : v;
        float ae = (jc < deg) ? aegc[(size_t)(r0 + jc) * 4 + h]
                              : aegc[((size_t)E + v) * 4 + h];
        float a = ssrc[s2 * 4 + h] + sd + ae;
        a = (a > 0.f) ? a : 0.2f * a;
        den += __expf(a - m);
      }
    }
    den += __shfl_xor(den, 4);
    den += __shfl_xor(den, 8);
    den += __shfl_xor(den, 16);
    den += __shfl_xor(den, 32);
    float rden = 1.f / den;
    for (int jb = 0; jb < ne; jb += 16) {
      int jc = jb + j;
      if (jc < ne) {
        int s2 = (jc < deg) ? srcs[r0 + jc] : v;
        int eo = (jc < deg) ? eidArr[r0 + jc] : E + v;
        float ae = (jc < deg) ? aegc[(size_t)(r0 + jc) * 4 + h]
                              : aegc[((size_t)E + v) * 4 + h];
        float a = ssrc[s2 * 4 + h] + sd + ae;
        a = (a > 0.f) ? a : 0.2f * a;
        alpha_out[(size_t)eo * 4 + h] = __expf(a - m) * rden;
      }
    }
    // aggregation with uniform per-edge recompute (no fence needed)
    float sdh = __shfl(sd, hh);
    float mh  = __shfl(m, hh);
    float rdh = __shfl(rden, hh);
    for (int jc = 0; jc < ne; jc++) {
      int s0 = (jc < deg) ? srcs[r0 + jc] : v;
      size_t ap = (jc < deg) ? (size_t)(r0 + jc) : (size_t)E + v;
      float a = ssrc[s0 * 4 + hh] + sdh + aegc[ap * 4 + hh];
      a = (a > 0.f) ? a : 0.2f * a;
      float al = __expf(a - mh) * rdh;
      uint2 u = *(const uint2*)(h_bf + (size_t)s0 * 256 + coff);
      acc0 += al * bf2f((unsigned short)(u.x & 0xffff));
      acc1 += al * bf2f((unsigned short)(u.x >> 16));
      acc2 += al * bf2f((unsigned short)(u.y & 0xffff));
      acc3 += al * bf2f((unsigned short)(u.y >> 16));
    }
  }

  // ---- head reduce: lanes {L, L+16, L+32, L+48} hold heads 0..3 ----
  acc0 += __shfl_xor(acc0, 16); acc0 += __shfl_xor(acc0, 32);
  acc1 += __shfl_xor(acc1, 16); acc1 += __shfl_xor(acc1, 32);
  acc2 += __shfl_xor(acc2, 16); acc2 += __shfl_xor(acc2, 32);
  acc3 += __shfl_xor(acc3, 16); acc3 += __shfl_xor(acc3, 32);

  // ---- epilogue in lanes 0..15: bias + leaky(0.01) + LayerNorm(64) ----
  float4 b4 = ((const float4*)bias)[lane & 15];
  float v0 = acc0 * 0.25f + b4.x;
  float v1 = acc1 * 0.25f + b4.y;
  float v2 = acc2 * 0.25f + b4.z;
  float v3 = acc3 * 0.25f + b4.w;
  v0 = (v0 > 0.f) ? v0 : 0.01f * v0;
  v1 = (v1 > 0.f) ? v1 : 0.01f * v1;
  v2 = (v2 > 0.f) ? v2 : 0.01f * v2;
  v3 = (v3 > 0.f) ? v3 : 0.01f * v3;
  float mu = v0 + v1 + v2 + v3;
  mu += __shfl_xor(mu, 1); mu += __shfl_xor(mu, 2);
  mu += __shfl_xor(mu, 4); mu += __shfl_xor(mu, 8);
  mu *= (1.f / 64.f);
  float d0 = v0 - mu, d1 = v1 - mu, d2 = v2 - mu, d3 = v3 - mu;
  float var = d0 * d0 + d1 * d1 + d2 * d2 + d3 * d3;
  var += __shfl_xor(var, 1); var += __shfl_xor(var, 2);
  var += __shfl_xor(var, 4); var += __shfl_xor(var, 8);
  var *= (1.f / 64.f);
  float rstd = rsqrtf(var + 1e-5f);
  if (lane < 16) {
    float4 g4 = ((const float4*)gamma)[lane];
    float4 be4 = ((const float4*)beta)[lane];
    float4 y = make_float4(d0 * rstd * g4.x + be4.x, d1 * rstd * g4.y + be4.y,
                           d2 * rstd * g4.z + be4.z, d3 * rstd * g4.w + be4.w);
    *(float4*)(xout + (size_t)v * HID + lane * 4) = y;
  }
}

extern "C" void kernel_launch(void* const* d_in, const int* in_sizes, int n_in,
                              void* d_out, int out_size, void* d_ws, size_t ws_size,
                              hipStream_t stream)
{
  const float* x     = (const float*)d_in[0];
  const int*   eidx  = (const int*)d_in[1];
  const float* eattr = (const float*)d_in[2];
  const float* wn    = (const float*)d_in[3];
  const float* bn    = (const float*)d_in[4];
  const float* we    = (const float*)d_in[5];
  const float* be    = (const float*)d_in[6];
  const float* lin1  = (const float*)d_in[7];
  const float* line1 = (const float*)d_in[8];
  const float* as1   = (const float*)d_in[9];
  const float* ad1   = (const float*)d_in[10];
  const float* ae1   = (const float*)d_in[11];
  const float* b1    = (const float*)d_in[12];
  const float* g1    = (const float*)d_in[13];
  const float* bt1   = (const float*)d_in[14];
  const float* lin2  = (const float*)d_in[15];
  const float* line2 = (const float*)d_in[16];
  const float* as2   = (const float*)d_in[17];
  const float* ad2   = (const float*)d_in[18];
  const float* ae2   = (const float*)d_in[19];
  const float* b2    = (const float*)d_in[20];
  const float* g2    = (const float*)d_in[21];
  const float* bt2   = (const float*)d_in[22];

  int n = in_sizes[0] / FN;
  int E = in_sizes[1] / 2;
  const int* srcA = eidx;
  const int* dstA = eidx + E;

  float* out_h2 = (float*)d_out;
  float* alpha1 = out_h2 + (size_t)n * HID;
  float* alpha2 = alpha1 + (size_t)(E + n) * 4;

  char* ws = (char*)d_ws;
  size_t off = 0;
  auto alloc = [&](size_t bytes) -> char* {
    char* p = ws + off;
    off += (bytes + 255) & ~(size_t)255;
    return p;
  };
  unsigned short* h_bf = (unsigned short*)alloc((size_t)n * 256 * 2);
  float* x1      = (float*)alloc((size_t)n * HID * 4);
  float* h1      = (float*)alloc((size_t)n * HID * 4);
  float* aeg1c   = (float*)alloc((size_t)(E + n) * 4 * 4);
  float* aeg2c   = (float*)alloc((size_t)(E + n) * 4 * 4);
  float* ssrc    = (float*)alloc((size_t)n * 4 * 4);
  float* sdst    = (float*)alloc((size_t)n * 4 * 4);
  float* vS      = (float*)alloc(512 * 4);
  float* vD      = (float*)alloc(512 * 4);
  float* vE      = (float*)alloc(512 * 4);
  int*   deg     = (int*)alloc((size_t)n * 4);
  int*   cnt     = (int*)alloc((size_t)n * 4);
  int*   rowptr  = (int*)alloc((size_t)(n + 1) * 4);
  int*   eid     = (int*)alloc((size_t)E * 4);
  int*   srcs    = (int*)alloc((size_t)E * 4);
  int*   perm    = (int*)alloc((size_t)E * 4);
  int*   bsum    = (int*)alloc(1024 * 4);
  int*   boff    = (int*)alloc(1024 * 4);

  hipMemsetAsync(deg, 0, (size_t)n * 4, stream);
  hipMemsetAsync(cnt, 0, (size_t)n * 4, stream);

  int nb = (n + 1023) / 1024;
  k_vecs<<<6, 256, 0, stream>>>(lin1, line1, as1, ad1, ae1,
                                lin2, line2, as2, ad2, ae2, vS, vD, vE);
  k_x1<<<(n + 3) / 4, 256, 0, stream>>>(x, wn, bn, vS, vD, x1, ssrc, sdst, n);
  k_deg<<<(E + 255) / 256, 256, 0, stream>>>(dstA, deg, E);
  k_scan1<<<nb, 1024, 0, stream>>>(deg, rowptr, bsum, n);
  k_scan2<<<1, 1024, 0, stream>>>(bsum, boff, rowptr, nb, n);
  k_scan3<<<nb, 1024, 0, stream>>>(rowptr, boff, n);
  k_fill<<<(E + 255) / 256, 256, 0, stream>>>(srcA, dstA, rowptr, cnt, eid, srcs, perm, E);
  k_aeg_e<<<(E + 255) / 256, 256, 0, stream>>>(eattr, we, be, vE, perm, aeg1c, aeg2c, E);
  k_self_aeg<<<(n + 31) / 32, 256, 0, stream>>>(rowptr, aeg1c, aeg2c, E, n);

  // layer 1
  k_h<<<(n + NPB - 1) / NPB, 256, 0, stream>>>(x1, lin1, h_bf, n);
  k_node<<<(n + 3) / 4, 256, 0, stream>>>(h_bf, ssrc, sdst, aeg1c, rowptr, eid, srcs,
                                          b1, g1, bt1, alpha1, h1, n, E);
  // layer 2
  k_sdots<<<(n + 3) / 4, 256, 0, stream>>>(h1, vS + 256, vD + 256, ssrc, sdst, n);
  k_h<<<(n + NPB - 1) / NPB, 256, 0, stream>>>(h1, lin2, h_bf, n);
  k_node<<<(n + 3) / 4, 256, 0, stream>>>(h_bf, ssrc, sdst, aeg2c, rowptr, eid, srcs,
                                          b2, g2, bt2, alpha2, out_h2, n, E);
}

// Round 7
// 228.214 us; speedup vs baseline: 3.1254x; 1.1069x over previous
//
#include <hip/hip_runtime.h>

#define FN 32
#define FE 16
#define HID 64
#define HEADS 4
#define CHC 64
// H*C = 256

typedef float f32x4 __attribute__((ext_vector_type(4)));

__device__ __forceinline__ float bf2f(unsigned short u) {
  unsigned int x = ((unsigned int)u) << 16;
  return __builtin_bit_cast(float, x);
}
__device__ __forceinline__ unsigned short f2bf(float f) {
  unsigned int x = __builtin_bit_cast(unsigned int, f);
  unsigned int r = (x + 0x7fff + ((x >> 16) & 1)) >> 16;   // RNE
  return (unsigned short)r;
}

// reduce 8 per-lane values over 64 lanes (array-halving butterfly, 10 shfl),
// then store entries 0..3 -> arr1[pos*4+h], 4..7 -> arr2[pos*4+h]
__device__ __forceinline__ void reduce8_store(const float p[8],
    float* __restrict__ arr1, float* __restrict__ arr2, size_t pos, int lane,
    float scale)
{
  float q[4];
  {
    bool hi = lane & 1;
    #pragma unroll
    for (int m = 0; m < 4; m++) {
      float keep = hi ? p[m + 4] : p[m];
      float send = hi ? p[m] : p[m + 4];
      q[m] = keep + __shfl_xor(send, 1);
    }
  }
  float r[2];
  {
    bool hi = lane & 2;
    #pragma unroll
    for (int m = 0; m < 2; m++) {
      float keep = hi ? q[m + 2] : q[m];
      float send = hi ? q[m] : q[m + 2];
      r[m] = keep + __shfl_xor(send, 2);
    }
  }
  float s;
  {
    bool hi = lane & 4;
    float keep = hi ? r[1] : r[0];
    float send = hi ? r[0] : r[1];
    s = keep + __shfl_xor(send, 4);
  }
  s += __shfl_xor(s, 8);
  s += __shfl_xor(s, 16);
  s += __shfl_xor(s, 32);
  if (lane < 8) {
    int entry = ((lane & 1) << 2) | (lane & 2) | ((lane >> 2) & 1);
    if (entry < 4) arr1[pos * 4 + entry] = s * scale;
    else           arr2[pos * 4 + entry - 4] = s * scale;
  }
}

// vS/vD/vE[l][c][h]: folded attention vectors. 6 blocks: (layer, kind)
__global__ __launch_bounds__(256) void k_vecs(
    const float* __restrict__ lin1, const float* __restrict__ line1,
    const float* __restrict__ as1, const float* __restrict__ ad1,
    const float* __restrict__ ae1,
    const float* __restrict__ lin2, const float* __restrict__ line2,
    const float* __restrict__ as2, const float* __restrict__ ad2,
    const float* __restrict__ ae2,
    float* __restrict__ vS, float* __restrict__ vD, float* __restrict__ vE)
{
  int bi = blockIdx.x;         // 0..5
  int l = bi / 3, kind = bi % 3;
  const float* lin = (kind == 2) ? (l ? line2 : line1) : (l ? lin2 : lin1);
  const float* att = (kind == 0) ? (l ? as2 : as1)
                   : (kind == 1) ? (l ? ad2 : ad1) : (l ? ae2 : ae1);
  float* out = ((kind == 0) ? vS : (kind == 1) ? vD : vE) + l * 256;
  int t = threadIdx.x;
  int c = t >> 2, hd = t & 3;
  float acc = 0.f;
  for (int cc = 0; cc < CHC; cc++)
    acc += lin[c * (HEADS * CHC) + hd * CHC + cc] * att[hd * CHC + cc];
  out[c * 4 + hd] = acc;
}

// x1 = relu(x @ wn + bn) + layer-1 att dots (x1 . vS1 / vD1)
__global__ __launch_bounds__(256) void k_x1(const float* __restrict__ x,
    const float* __restrict__ wn, const float* __restrict__ bn,
    const float* __restrict__ vS, const float* __restrict__ vD,
    float* __restrict__ x1, float* __restrict__ ssrc, float* __restrict__ sdst,
    int n)
{
  int t = threadIdx.x; int w = t >> 6; int lane = t & 63;
  int v = blockIdx.x * 4 + w;
  __shared__ float xs[4][FN];
  if (v < n && lane < FN) xs[w][lane] = x[(size_t)v * FN + lane];
  __syncthreads();
  if (v >= n) return;
  float acc = bn[lane];
  #pragma unroll
  for (int k = 0; k < FN; k++) acc += xs[w][k] * wn[k * HID + lane];
  acc = fmaxf(acc, 0.f);
  x1[(size_t)v * HID + lane] = acc;
  float4 s4 = ((const float4*)vS)[lane];
  float4 d4 = ((const float4*)vD)[lane];
  float p[8] = {acc * s4.x, acc * s4.y, acc * s4.z, acc * s4.w,
                acc * d4.x, acc * d4.y, acc * d4.z, acc * d4.w};
  reduce8_store(p, ssrc, sdst, (size_t)v, lane, 1.f);
}

__global__ __launch_bounds__(256) void k_deg(const int* __restrict__ dst,
                                             int* __restrict__ deg, int E)
{
  int e = blockIdx.x * 256 + threadIdx.x;
  if (e < E) atomicAdd(&deg[dst[e]], 1);
}

// ---- 3-kernel exclusive scan of deg -> rowptr ----
__global__ __launch_bounds__(1024) void k_scan1(const int* __restrict__ deg,
    int* __restrict__ rowptr, int* __restrict__ bsum, int n)
{
  __shared__ int wsum[16];
  int t = threadIdx.x, wv = t >> 6, lane = t & 63;
  int i = blockIdx.x * 1024 + t;
  int val = (i < n) ? deg[i] : 0;
  int sc = val;
  #pragma unroll
  for (int off = 1; off < 64; off <<= 1) {
    int u = __shfl_up(sc, off);
    if (lane >= off) sc += u;
  }
  if (lane == 63) wsum[wv] = sc;
  __syncthreads();
  int woff = 0;
  #pragma unroll
  for (int k = 0; k < 16; k++) woff += (k < wv) ? wsum[k] : 0;
  if (i < n) rowptr[i] = woff + sc - val;
  if (t == 0) {
    int tot = 0;
    #pragma unroll
    for (int k = 0; k < 16; k++) tot += wsum[k];
    bsum[blockIdx.x] = tot;
  }
}

__global__ __launch_bounds__(1024) void k_scan2(const int* __restrict__ bsum,
    int* __restrict__ boff, int* __restrict__ rowptr, int nb, int n)
{
  __shared__ int wsum[16];
  int t = threadIdx.x, wv = t >> 6, lane = t & 63;
  int val = (t < nb) ? bsum[t] : 0;
  int sc = val;
  #pragma unroll
  for (int off = 1; off < 64; off <<= 1) {
    int u = __shfl_up(sc, off);
    if (lane >= off) sc += u;
  }
  if (lane == 63) wsum[wv] = sc;
  __syncthreads();
  int woff = 0;
  #pragma unroll
  for (int k = 0; k < 16; k++) woff += (k < wv) ? wsum[k] : 0;
  if (t < nb) boff[t] = woff + sc - val;
  if (t == 0) {
    int tot = 0;
    #pragma unroll
    for (int k = 0; k < 16; k++) tot += wsum[k];
    rowptr[n] = tot;
  }
}

__global__ __launch_bounds__(1024) void k_scan3(int* __restrict__ rowptr,
    const int* __restrict__ boff, int n)
{
  int i = blockIdx.x * 1024 + threadIdx.x;
  if (i < n) rowptr[i] += boff[blockIdx.x];
}

// CSR fill
__global__ __launch_bounds__(256) void k_fill(const int* __restrict__ src,
    const int* __restrict__ dst, const int* __restrict__ rowptr,
    int* __restrict__ cnt, int* __restrict__ eid, int* __restrict__ srcs,
    int* __restrict__ perm, int E)
{
  int e = blockIdx.x * 256 + threadIdx.x;
  if (e < E) {
    int d = dst[e];
    int pos = rowptr[d] + atomicAdd(&cnt[d], 1);
    eid[pos] = e;
    srcs[pos] = src[e];
    perm[e] = pos;
  }
}

// a_edge for real edges, lane-owns-edge, weights broadcast from LDS.
__global__ __launch_bounds__(256) void k_aeg_e(const float* __restrict__ eattr,
    const float* __restrict__ we, const float* __restrict__ be,
    const float* __restrict__ vE, const int* __restrict__ perm,
    float* __restrict__ aeg1, float* __restrict__ aeg2, int E)
{
  __shared__ float4 we_t4[HID][4];
  __shared__ float4 vE_s[2][HID];
  __shared__ float  be_s[HID];
  int t = threadIdx.x;
  for (int i = t; i < FE * HID; i += 256) {
    int k = i >> 6, c = i & 63;
    ((float*)we_t4)[c * 16 + k] = we[i];
  }
  for (int i = t; i < 512; i += 256) ((float*)vE_s)[i] = vE[i];
  if (t < HID) be_s[t] = be[t];
  __syncthreads();

  int e = blockIdx.x * 256 + t;
  if (e >= E) return;
  const float4* er = (const float4*)(eattr + (size_t)e * FE);
  float4 A = er[0], B = er[1], C4 = er[2], D = er[3];
  float ta[FE] = {A.x, A.y, A.z, A.w, B.x, B.y, B.z, B.w,
                  C4.x, C4.y, C4.z, C4.w, D.x, D.y, D.z, D.w};
  float4 acc1 = make_float4(0.f, 0.f, 0.f, 0.f);
  float4 acc2 = make_float4(0.f, 0.f, 0.f, 0.f);
  #pragma unroll 4
  for (int c = 0; c < HID; c++) {
    float4 w0 = we_t4[c][0], w1 = we_t4[c][1], w2 = we_t4[c][2], w3 = we_t4[c][3];
    float ea = be_s[c];
    ea += ta[0] * w0.x + ta[1] * w0.y + ta[2] * w0.z + ta[3] * w0.w;
    ea += ta[4] * w1.x + ta[5] * w1.y + ta[6] * w1.z + ta[7] * w1.w;
    ea += ta[8] * w2.x + ta[9] * w2.y + ta[10] * w2.z + ta[11] * w2.w;
    ea += ta[12] * w3.x + ta[13] * w3.y + ta[14] * w3.z + ta[15] * w3.w;
    ea = fmaxf(ea, 0.f);
    float4 u1 = vE_s[0][c], u2 = vE_s[1][c];
    acc1.x += ea * u1.x; acc1.y += ea * u1.y; acc1.z += ea * u1.z; acc1.w += ea * u1.w;
    acc2.x += ea * u2.x; acc2.y += ea * u2.y; acc2.z += ea * u2.z; acc2.w += ea * u2.w;
  }
  int pos = perm[e];
  *(float4*)(aeg1 + (size_t)pos * 4) = acc1;
  *(float4*)(aeg2 + (size_t)pos * 4) = acc2;
}

// self-loop a_edge = segment-mean of CSR aeg values
__global__ __launch_bounds__(256) void k_self_aeg(const int* __restrict__ rowptr,
    float* __restrict__ aeg1, float* __restrict__ aeg2, int E, int n)
{
  int t = threadIdx.x;
  int v = blockIdx.x * 32 + (t >> 3);
  if (v >= n) return;
  int ent = t & 7;
  int h = ent & 3;
  const float* srcp = (ent < 4) ? aeg1 : aeg2;
  int r0 = rowptr[v], r1 = rowptr[v + 1];
  float s = 0.f;
  for (int j = r0; j < r1; j++) s += srcp[(size_t)j * 4 + h];
  float m = s / fmaxf((float)(r1 - r0), 1.f);
  if (ent < 4) aeg1[((size_t)E + v) * 4 + h] = m;
  else         aeg2[((size_t)E + v) * 4 + h] = m;
}

// h(bf16) = x @ lin  [n,256], 16 nodes/block. Pure GEMM.
#define NPB 16
__global__ __launch_bounds__(256) void k_h(const float* __restrict__ xin,
    const float* __restrict__ lin, unsigned short* __restrict__ h_bf, int n)
{
  int t = threadIdx.x;
  int v0 = blockIdx.x * NPB;
  __shared__ float xs[NPB][HID];
  for (int i = t; i < NPB * HID; i += 256) {
    int vv = v0 + (i >> 6);
    xs[i >> 6][i & 63] = (vv < n) ? xin[(size_t)vv * HID + (i & 63)] : 0.f;
  }
  __syncthreads();
  float acc[NPB];
  #pragma unroll
  for (int i = 0; i < NPB; i++) acc[i] = 0.f;
  for (int k = 0; k < HID; k++) {
    float lv = lin[k * 256 + t];
    #pragma unroll
    for (int i = 0; i < NPB; i++) acc[i] += xs[i][k] * lv;
  }
  #pragma unroll
  for (int i = 0; i < NPB; i++) {
    int v = v0 + i;
    if (v < n) h_bf[(size_t)v * 256 + t] = f2bf(acc[i]);
  }
}

// Fused per-node: softmax + alpha + aggregation + head-mean + bias + leaky +
// LayerNorm (+ optional fused next-layer att dots). WAVE per node.
template<bool DOTS>
__global__ __launch_bounds__(256) void k_node(
    const unsigned short* __restrict__ h_bf, const float* __restrict__ ssrc,
    const float* __restrict__ sdst, const float* __restrict__ aegc,
    const int* __restrict__ rowptr, const int* __restrict__ eidArr,
    const int* __restrict__ srcs, const float* __restrict__ bias,
    const float* __restrict__ gamma, const float* __restrict__ beta,
    const float* __restrict__ vS2, const float* __restrict__ vD2,
    float* __restrict__ alpha_out, float* __restrict__ xout,
    float* __restrict__ ssrc_o, float* __restrict__ sdst_o, int n, int E)
{
  __shared__ float als[4][64][4];   // per-wave alpha exchange
  int t = threadIdx.x; int wv = t >> 6, lane = t & 63;
  int v = blockIdx.x * 4 + wv;
  if (v >= n) return;
  int r0 = rowptr[v], r1 = rowptr[v + 1];
  int deg = r1 - r0, ne = deg + 1;      // + self loop (edge id E+v, src v)
  int coff = lane * 4;                  // aggregation: 4 channels per lane
  int hh = lane >> 4;                   // head owning those channels
  float acc0 = 0.f, acc1 = 0.f, acc2 = 0.f, acc3 = 0.f;
  const float4* aeg4 = (const float4*)aegc;
  const float4* ss4p = (const float4*)ssrc;
  float4 sd4 = ((const float4*)sdst)[v];

  if (ne <= 64) {
    // ---- lane = edge; all 4 heads per lane ----
    int s = v, eo = E + v;
    if (lane < deg) { s = srcs[r0 + lane]; eo = eidArr[r0 + lane]; }
    bool valid = (lane < ne);
    float a0 = -INFINITY, a1 = -INFINITY, a2 = -INFINITY, a3 = -INFINITY;
    if (valid) {
      float4 ae4 = aeg4[(lane < deg) ? (r0 + lane) : (E + v)];
      float4 ss4 = ss4p[s];
      a0 = ss4.x + sd4.x + ae4.x; a0 = (a0 > 0.f) ? a0 : 0.2f * a0;
      a1 = ss4.y + sd4.y + ae4.y; a1 = (a1 > 0.f) ? a1 : 0.2f * a1;
      a2 = ss4.z + sd4.z + ae4.z; a2 = (a2 > 0.f) ? a2 : 0.2f * a2;
      a3 = ss4.w + sd4.w + ae4.w; a3 = (a3 > 0.f) ? a3 : 0.2f * a3;
    }
    // ---- max reduce: array-halving (head at lane L = 2*(L&1)+((L>>1)&1)) ----
    float m0, m1, m2, m3;
    {
      bool hi0 = lane & 1;
      float k0 = hi0 ? a2 : a0, s0 = hi0 ? a0 : a2;
      float k1 = hi0 ? a3 : a1, s1 = hi0 ? a1 : a3;
      float q0 = fmaxf(k0, __shfl_xor(s0, 1));
      float q1 = fmaxf(k1, __shfl_xor(s1, 1));
      bool hi1 = lane & 2;
      float k2 = hi1 ? q1 : q0, s2 = hi1 ? q0 : q1;
      float r = fmaxf(k2, __shfl_xor(s2, 2));
      r = fmaxf(r, __shfl_xor(r, 4));
      r = fmaxf(r, __shfl_xor(r, 8));
      r = fmaxf(r, __shfl_xor(r, 16));
      r = fmaxf(r, __shfl_xor(r, 32));
      m0 = __shfl(r, 0); m1 = __shfl(r, 2); m2 = __shfl(r, 1); m3 = __shfl(r, 3);
    }
    float e0 = __expf(a0 - m0), e1 = __expf(a1 - m1);
    float e2 = __expf(a2 - m2), e3 = __expf(a3 - m3);
    float d0, d1, d2, d3;
    {
      bool hi0 = lane & 1;
      float k0 = hi0 ? e2 : e0, s0 = hi0 ? e0 : e2;
      float k1 = hi0 ? e3 : e1, s1 = hi0 ? e1 : e3;
      float q0 = k0 + __shfl_xor(s0, 1);
      float q1 = k1 + __shfl_xor(s1, 1);
      bool hi1 = lane & 2;
      float k2 = hi1 ? q1 : q0, s2 = hi1 ? q0 : q1;
      float r = k2 + __shfl_xor(s2, 2);
      r += __shfl_xor(r, 4);
      r += __shfl_xor(r, 8);
      r += __shfl_xor(r, 16);
      r += __shfl_xor(r, 32);
      d0 = __shfl(r, 0); d1 = __shfl(r, 2); d2 = __shfl(r, 1); d3 = __shfl(r, 3);
    }
    float4 alf = make_float4(e0 / d0, e1 / d1, e2 / d2, e3 / d3);
    if (valid) {
      f32x4 alv = {alf.x, alf.y, alf.z, alf.w};
      __builtin_nontemporal_store(alv, (f32x4*)alpha_out + eo);
    }
    *(float4*)als[wv][lane] = alf;
    __builtin_amdgcn_wave_barrier();
    __builtin_amdgcn_sched_barrier(0);
    // ---- aggregation: 4 loads in flight ----
    int jj = 0;
    for (; jj + 3 < ne; jj += 4) {
      int s0 = __shfl(s, jj), s1 = __shfl(s, jj + 1);
      int s2 = __shfl(s, jj + 2), s3 = __shfl(s, jj + 3);
      float al0 = als[wv][jj][hh],     al1 = als[wv][jj + 1][hh];
      float al2 = als[wv][jj + 2][hh], al3 = als[wv][jj + 3][hh];
      uint2 u0 = *(const uint2*)(h_bf + (size_t)s0 * 256 + coff);
      uint2 u1 = *(const uint2*)(h_bf + (size_t)s1 * 256 + coff);
      uint2 u2 = *(const uint2*)(h_bf + (size_t)s2 * 256 + coff);
      uint2 u3 = *(const uint2*)(h_bf + (size_t)s3 * 256 + coff);
      acc0 += al0 * bf2f((unsigned short)(u0.x & 0xffff))
            + al1 * bf2f((unsigned short)(u1.x & 0xffff))
            + al2 * bf2f((unsigned short)(u2.x & 0xffff))
            + al3 * bf2f((unsigned short)(u3.x & 0xffff));
      acc1 += al0 * bf2f((unsigned short)(u0.x >> 16))
            + al1 * bf2f((unsigned short)(u1.x >> 16))
            + al2 * bf2f((unsigned short)(u2.x >> 16))
            + al3 * bf2f((unsigned short)(u3.x >> 16));
      acc2 += al0 * bf2f((unsigned short)(u0.y & 0xffff))
            + al1 * bf2f((unsigned short)(u1.y & 0xffff))
            + al2 * bf2f((unsigned short)(u2.y & 0xffff))
            + al3 * bf2f((unsigned short)(u3.y & 0xffff));
      acc3 += al0 * bf2f((unsigned short)(u0.y >> 16))
            + al1 * bf2f((unsigned short)(u1.y >> 16))
            + al2 * bf2f((unsigned short)(u2.y >> 16))
            + al3 * bf2f((unsigned short)(u3.y >> 16));
    }
    for (; jj < ne; jj++) {
      int s0 = __shfl(s, jj);
      float al0 = als[wv][jj][hh];
      uint2 u0 = *(const uint2*)(h_bf + (size_t)s0 * 256 + coff);
      acc0 += al0 * bf2f((unsigned short)(u0.x & 0xffff));
      acc1 += al0 * bf2f((unsigned short)(u0.x >> 16));
      acc2 += al0 * bf2f((unsigned short)(u0.y & 0xffff));
      acc3 += al0 * bf2f((unsigned short)(u0.y >> 16));
    }
  } else {
    // ---- chunked two-pass fallback (deg > 63, rare) ----
    int j4 = lane >> 2, hb = lane & 3;
    float sd = sdst[v * 4 + hb];
    float m = -INFINITY;
    for (int jb = 0; jb < ne; jb += 16) {
      int jc = jb + j4;
      if (jc < ne) {
        int s2 = (jc < deg) ? srcs[r0 + jc] : v;
        float ae = (jc < deg) ? aegc[(size_t)(r0 + jc) * 4 + hb]
                              : aegc[((size_t)E + v) * 4 + hb];
        float a = ssrc[s2 * 4 + hb] + sd + ae;
        a = (a > 0.f) ? a : 0.2f * a;
        m = fmaxf(m, a);
      }
    }
    m = fmaxf(m, __shfl_xor(m, 4));
    m = fmaxf(m, __shfl_xor(m, 8));
    m = fmaxf(m, __shfl_xor(m, 16));
    m = fmaxf(m, __shfl_xor(m, 32));
    float den = 0.f;
    for (int jb = 0; jb < ne; jb += 16) {
      int jc = jb + j4;
      if (jc < ne) {
        int s2 = (jc < deg) ? srcs[r0 + jc] : v;
        float ae = (jc < deg) ? aegc[(size_t)(r0 + jc) * 4 + hb]
                              : aegc[((size_t)E + v) * 4 + hb];
        float a = ssrc[s2 * 4 + hb] + sd + ae;
        a = (a > 0.f) ? a : 0.2f * a;
        den += __expf(a - m);
      }
    }
    den += __shfl_xor(den, 4);
    den += __shfl_xor(den, 8);
    den += __shfl_xor(den, 16);
    den += __shfl_xor(den, 32);
    float rden = 1.f / den;
    for (int jb = 0; jb < ne; jb += 16) {
      int jc = jb + j4;
      if (jc < ne) {
        int s2 = (jc < deg) ? srcs[r0 + jc] : v;
        int eo = (jc < deg) ? eidArr[r0 + jc] : E + v;
        float ae = (jc < deg) ? aegc[(size_t)(r0 + jc) * 4 + hb]
                              : aegc[((size_t)E + v) * 4 + hb];
        float a = ssrc[s2 * 4 + hb] + sd + ae;
        a = (a > 0.f) ? a : 0.2f * a;
        alpha_out[(size_t)eo * 4 + hb] = __expf(a - m) * rden;
      }
    }
    float sdh = __shfl(sd, hh);
    float mh  = __shfl(m, hh);
    float rdh = __shfl(rden, hh);
    for (int jc = 0; jc < ne; jc++) {
      int s0 = (jc < deg) ? srcs[r0 + jc] : v;
      size_t ap = (jc < deg) ? (size_t)(r0 + jc) : (size_t)E + v;
      float a = ssrc[s0 * 4 + hh] + sdh + aegc[ap * 4 + hh];
      a = (a > 0.f) ? a : 0.2f * a;
      float al = __expf(a - mh) * rdh;
      uint2 u = *(const uint2*)(h_bf + (size_t)s0 * 256 + coff);
      acc0 += al * bf2f((unsigned short)(u.x & 0xffff));
      acc1 += al * bf2f((unsigned short)(u.x >> 16));
      acc2 += al * bf2f((unsigned short)(u.y & 0xffff));
      acc3 += al * bf2f((unsigned short)(u.y >> 16));
    }
  }

  // ---- head reduce: lanes {L, L+16, L+32, L+48} hold heads 0..3 ----
  acc0 += __shfl_xor(acc0, 16); acc0 += __shfl_xor(acc0, 32);
  acc1 += __shfl_xor(acc1, 16); acc1 += __shfl_xor(acc1, 32);
  acc2 += __shfl_xor(acc2, 16); acc2 += __shfl_xor(acc2, 32);
  acc3 += __shfl_xor(acc3, 16); acc3 += __shfl_xor(acc3, 32);

  // ---- epilogue: bias + leaky(0.01) + LayerNorm(64); all lanes hold copy ----
  int c16 = lane & 15;
  float4 b4 = ((const float4*)bias)[c16];
  float v0 = acc0 * 0.25f + b4.x;
  float v1 = acc1 * 0.25f + b4.y;
  float v2 = acc2 * 0.25f + b4.z;
  float v3 = acc3 * 0.25f + b4.w;
  v0 = (v0 > 0.f) ? v0 : 0.01f * v0;
  v1 = (v1 > 0.f) ? v1 : 0.01f * v1;
  v2 = (v2 > 0.f) ? v2 : 0.01f * v2;
  v3 = (v3 > 0.f) ? v3 : 0.01f * v3;
  float mu = v0 + v1 + v2 + v3;
  mu += __shfl_xor(mu, 1); mu += __shfl_xor(mu, 2);
  mu += __shfl_xor(mu, 4); mu += __shfl_xor(mu, 8);
  mu *= (1.f / 64.f);
  float d0 = v0 - mu, d1 = v1 - mu, d2 = v2 - mu, d3 = v3 - mu;
  float var = d0 * d0 + d1 * d1 + d2 * d2 + d3 * d3;
  var += __shfl_xor(var, 1); var += __shfl_xor(var, 2);
  var += __shfl_xor(var, 4); var += __shfl_xor(var, 8);
  var *= (1.f / 64.f);
  float rstd = rsqrtf(var + 1e-5f);
  float4 g4 = ((const float4*)gamma)[c16];
  float4 be4 = ((const float4*)beta)[c16];
  float y0 = d0 * rstd * g4.x + be4.x;
  float y1 = d1 * rstd * g4.y + be4.y;
  float y2 = d2 * rstd * g4.z + be4.z;
  float y3 = d3 * rstd * g4.w + be4.w;
  if (lane < 16) {
    float4 y = make_float4(y0, y1, y2, y3);
    *(float4*)(xout + (size_t)v * HID + lane * 4) = y;
  }
  if constexpr (DOTS) {
    // next-layer att dots: p_h = y . vS2[:,h] (4 wave-copies -> scale 0.25)
    int c0 = c16 * 4;
    float4 vs0 = ((const float4*)vS2)[c0],     vs1 = ((const float4*)vS2)[c0 + 1];
    float4 vs2 = ((const float4*)vS2)[c0 + 2], vs3 = ((const float4*)vS2)[c0 + 3];
    float4 vd0 = ((const float4*)vD2)[c0],     vd1 = ((const float4*)vD2)[c0 + 1];
    float4 vd2 = ((const float4*)vD2)[c0 + 2], vd3 = ((const float4*)vD2)[c0 + 3];
    float p[8];
    p[0] = y0 * vs0.x + y1 * vs1.x + y2 * vs2.x + y3 * vs3.x;
    p[1] = y0 * vs0.y + y1 * vs1.y + y2 * vs2.y + y3 * vs3.y;
    p[2] = y0 * vs0.z + y1 * vs1.z + y2 * vs2.z + y3 * vs3.z;
    p[3] = y0 * vs0.w + y1 * vs1.w + y2 * vs2.w + y3 * vs3.w;
    p[4] = y0 * vd0.x + y1 * vd1.x + y2 * vd2.x + y3 * vd3.x;
    p[5] = y0 * vd0.y + y1 * vd1.y + y2 * vd2.y + y3 * vd3.y;
    p[6] = y0 * vd0.z + y1 * vd1.z + y2 * vd2.z + y3 * vd3.z;
    p[7] = y0 * vd0.w + y1 * vd1.w + y2 * vd2.w + y3 * vd3.w;
    reduce8_store(p, ssrc_o, sdst_o, (size_t)v, lane, 0.25f);
  }
}

extern "C" void kernel_launch(void* const* d_in, const int* in_sizes, int n_in,
                              void* d_out, int out_size, void* d_ws, size_t ws_size,
                              hipStream_t stream)
{
  const float* x     = (const float*)d_in[0];
  const int*   eidx  = (const int*)d_in[1];
  const float* eattr = (const float*)d_in[2];
  const float* wn    = (const float*)d_in[3];
  const float* bn    = (const float*)d_in[4];
  const float* we    = (const float*)d_in[5];
  const float* be    = (const float*)d_in[6];
  const float* lin1  = (const float*)d_in[7];
  const float* line1 = (const float*)d_in[8];
  const float* as1   = (const float*)d_in[9];
  const float* ad1   = (const float*)d_in[10];
  const float* ae1   = (const float*)d_in[11];
  const float* b1    = (const float*)d_in[12];
  const float* g1    = (const float*)d_in[13];
  const float* bt1   = (const float*)d_in[14];
  const float* lin2  = (const float*)d_in[15];
  const float* line2 = (const float*)d_in[16];
  const float* as2   = (const float*)d_in[17];
  const float* ad2   = (const float*)d_in[18];
  const float* ae2   = (const float*)d_in[19];
  const float* b2    = (const float*)d_in[20];
  const float* g2    = (const float*)d_in[21];
  const float* bt2   = (const float*)d_in[22];

  int n = in_sizes[0] / FN;
  int E = in_sizes[1] / 2;
  const int* srcA = eidx;
  const int* dstA = eidx + E;

  float* out_h2 = (float*)d_out;
  float* alpha1 = out_h2 + (size_t)n * HID;
  float* alpha2 = alpha1 + (size_t)(E + n) * 4;

  char* ws = (char*)d_ws;
  size_t off = 0;
  auto alloc = [&](size_t bytes) -> char* {
    char* p = ws + off;
    off += (bytes + 255) & ~(size_t)255;
    return p;
  };
  unsigned short* h_bf = (unsigned short*)alloc((size_t)n * 256 * 2);
  float* x1      = (float*)alloc((size_t)n * HID * 4);
  float* h1      = (float*)alloc((size_t)n * HID * 4);
  float* aeg1c   = (float*)alloc((size_t)(E + n) * 4 * 4);
  float* aeg2c   = (float*)alloc((size_t)(E + n) * 4 * 4);
  float* ssrc1   = (float*)alloc((size_t)n * 4 * 4);
  float* sdst1   = (float*)alloc((size_t)n * 4 * 4);
  float* ssrc2   = (float*)alloc((size_t)n * 4 * 4);
  float* sdst2   = (float*)alloc((size_t)n * 4 * 4);
  float* vS      = (float*)alloc(512 * 4);
  float* vD      = (float*)alloc(512 * 4);
  float* vE      = (float*)alloc(512 * 4);
  int*   deg     = (int*)alloc((size_t)n * 4);
  int*   cnt     = (int*)alloc((size_t)n * 4);
  int*   rowptr  = (int*)alloc((size_t)(n + 1) * 4);
  int*   eid     = (int*)alloc((size_t)E * 4);
  int*   srcs    = (int*)alloc((size_t)E * 4);
  int*   perm    = (int*)alloc((size_t)E * 4);
  int*   bsum    = (int*)alloc(1024 * 4);
  int*   boff    = (int*)alloc(1024 * 4);

  hipMemsetAsync(deg, 0, (size_t)n * 4, stream);
  hipMemsetAsync(cnt, 0, (size_t)n * 4, stream);

  int nb = (n + 1023) / 1024;
  k_vecs<<<6, 256, 0, stream>>>(lin1, line1, as1, ad1, ae1,
                                lin2, line2, as2, ad2, ae2, vS, vD, vE);
  k_x1<<<(n + 3) / 4, 256, 0, stream>>>(x, wn, bn, vS, vD, x1, ssrc1, sdst1, n);
  k_deg<<<(E + 255) / 256, 256, 0, stream>>>(dstA, deg, E);
  k_scan1<<<nb, 1024, 0, stream>>>(deg, rowptr, bsum, n);
  k_scan2<<<1, 1024, 0, stream>>>(bsum, boff, rowptr, nb, n);
  k_scan3<<<nb, 1024, 0, stream>>>(rowptr, boff, n);
  k_fill<<<(E + 255) / 256, 256, 0, stream>>>(srcA, dstA, rowptr, cnt, eid, srcs, perm, E);
  k_aeg_e<<<(E + 255) / 256, 256, 0, stream>>>(eattr, we, be, vE, perm, aeg1c, aeg2c, E);
  k_self_aeg<<<(n + 31) / 32, 256, 0, stream>>>(rowptr, aeg1c, aeg2c, E, n);

  // layer 1 (fuses layer-2 att dots into epilogue)
  k_h<<<(n + NPB - 1) / NPB, 256, 0, stream>>>(x1, lin1, h_bf, n);
  k_node<true><<<(n + 3) / 4, 256, 0, stream>>>(h_bf, ssrc1, sdst1, aeg1c,
      rowptr, eid, srcs, b1, g1, bt1, vS + 256, vD + 256,
      alpha1, h1, ssrc2, sdst2, n, E);
  // layer 2
  k_h<<<(n + NPB - 1) / NPB, 256, 0, stream>>>(h1, lin2, h_bf, n);
  k_node<false><<<(n + 3) / 4, 256, 0, stream>>>(h_bf, ssrc2, sdst2, aeg2c,
      rowptr, eid, srcs, b2, g2, bt2, nullptr, nullptr,
      alpha2, out_h2, nullptr, nullptr, n, E);
}

// Round 8
// 223.872 us; speedup vs baseline: 3.1860x; 1.0194x over previous
//
#include <hip/hip_runtime.h>

#define FN 32
#define FE 16
#define HID 64
#define HEADS 4
#define CHC 64
// H*C = 256

typedef float f32x4 __attribute__((ext_vector_type(4)));

__device__ __forceinline__ float bf2f(unsigned short u) {
  unsigned int x = ((unsigned int)u) << 16;
  return __builtin_bit_cast(float, x);
}
__device__ __forceinline__ unsigned short f2bf(float f) {
  unsigned int x = __builtin_bit_cast(unsigned int, f);
  unsigned int r = (x + 0x7fff + ((x >> 16) & 1)) >> 16;   // RNE
  return (unsigned short)r;
}
__device__ __forceinline__ unsigned int pack2bf(float a, float b) {
  return (unsigned int)f2bf(a) | ((unsigned int)f2bf(b) << 16);
}

// reduce 8 per-lane values over 64 lanes (array-halving butterfly, 10 shfl),
// then store entries 0..3 -> arr1[pos*4+h], 4..7 -> arr2[pos*4+h]
__device__ __forceinline__ void reduce8_store(const float p[8],
    float* __restrict__ arr1, float* __restrict__ arr2, size_t pos, int lane,
    float scale)
{
  float q[4];
  {
    bool hi = lane & 1;
    #pragma unroll
    for (int m = 0; m < 4; m++) {
      float keep = hi ? p[m + 4] : p[m];
      float send = hi ? p[m] : p[m + 4];
      q[m] = keep + __shfl_xor(send, 1);
    }
  }
  float r[2];
  {
    bool hi = lane & 2;
    #pragma unroll
    for (int m = 0; m < 2; m++) {
      float keep = hi ? q[m + 2] : q[m];
      float send = hi ? q[m] : q[m + 2];
      r[m] = keep + __shfl_xor(send, 2);
    }
  }
  float s;
  {
    bool hi = lane & 4;
    float keep = hi ? r[1] : r[0];
    float send = hi ? r[0] : r[1];
    s = keep + __shfl_xor(send, 4);
  }
  s += __shfl_xor(s, 8);
  s += __shfl_xor(s, 16);
  s += __shfl_xor(s, 32);
  if (lane < 8) {
    int entry = ((lane & 1) << 2) | (lane & 2) | ((lane >> 2) & 1);
    if (entry < 4) arr1[pos * 4 + entry] = s * scale;
    else           arr2[pos * 4 + entry - 4] = s * scale;
  }
}

// vS/vD/vE[l][c][h]: folded attention vectors. 6 blocks: (layer, kind)
__global__ __launch_bounds__(256) void k_vecs(
    const float* __restrict__ lin1, const float* __restrict__ line1,
    const float* __restrict__ as1, const float* __restrict__ ad1,
    const float* __restrict__ ae1,
    const float* __restrict__ lin2, const float* __restrict__ line2,
    const float* __restrict__ as2, const float* __restrict__ ad2,
    const float* __restrict__ ae2,
    float* __restrict__ vS, float* __restrict__ vD, float* __restrict__ vE)
{
  int bi = blockIdx.x;         // 0..5
  int l = bi / 3, kind = bi % 3;
  const float* lin = (kind == 2) ? (l ? line2 : line1) : (l ? lin2 : lin1);
  const float* att = (kind == 0) ? (l ? as2 : as1)
                   : (kind == 1) ? (l ? ad2 : ad1) : (l ? ae2 : ae1);
  float* out = ((kind == 0) ? vS : (kind == 1) ? vD : vE) + l * 256;
  int t = threadIdx.x;
  int c = t >> 2, hd = t & 3;
  float acc = 0.f;
  for (int cc = 0; cc < CHC; cc++)
    acc += lin[c * (HEADS * CHC) + hd * CHC + cc] * att[hd * CHC + cc];
  out[c * 4 + hd] = acc;
}

// x1 = relu(x @ wn + bn) + layer-1 att dots (x1 . vS1 / vD1)
__global__ __launch_bounds__(256) void k_x1(const float* __restrict__ x,
    const float* __restrict__ wn, const float* __restrict__ bn,
    const float* __restrict__ vS, const float* __restrict__ vD,
    float* __restrict__ x1, float* __restrict__ ssrc, float* __restrict__ sdst,
    int n)
{
  int t = threadIdx.x; int w = t >> 6; int lane = t & 63;
  int v = blockIdx.x * 4 + w;
  __shared__ float xs[4][FN];
  if (v < n && lane < FN) xs[w][lane] = x[(size_t)v * FN + lane];
  __syncthreads();
  if (v >= n) return;
  float acc = bn[lane];
  #pragma unroll
  for (int k = 0; k < FN; k++) acc += xs[w][k] * wn[k * HID + lane];
  acc = fmaxf(acc, 0.f);
  x1[(size_t)v * HID + lane] = acc;
  float4 s4 = ((const float4*)vS)[lane];
  float4 d4 = ((const float4*)vD)[lane];
  float p[8] = {acc * s4.x, acc * s4.y, acc * s4.z, acc * s4.w,
                acc * d4.x, acc * d4.y, acc * d4.z, acc * d4.w};
  reduce8_store(p, ssrc, sdst, (size_t)v, lane, 1.f);
}

__global__ __launch_bounds__(256) void k_deg(const int* __restrict__ dst,
                                             int* __restrict__ deg, int E)
{
  int e = blockIdx.x * 256 + threadIdx.x;
  if (e < E) atomicAdd(&deg[dst[e]], 1);
}

// ---- scan kernels: per-block scan + fused block-offset apply ----
__global__ __launch_bounds__(1024) void k_scan1(const int* __restrict__ deg,
    int* __restrict__ rowptr, int* __restrict__ bsum, int n)
{
  __shared__ int wsum[16];
  int t = threadIdx.x, wv = t >> 6, lane = t & 63;
  int i = blockIdx.x * 1024 + t;
  int val = (i < n) ? deg[i] : 0;
  int sc = val;
  #pragma unroll
  for (int off = 1; off < 64; off <<= 1) {
    int u = __shfl_up(sc, off);
    if (lane >= off) sc += u;
  }
  if (lane == 63) wsum[wv] = sc;
  __syncthreads();
  int woff = 0;
  #pragma unroll
  for (int k = 0; k < 16; k++) woff += (k < wv) ? wsum[k] : 0;
  if (i < n) rowptr[i] = woff + sc - val;
  if (t == 0) {
    int tot = 0;
    #pragma unroll
    for (int k = 0; k < 16; k++) tot += wsum[k];
    bsum[blockIdx.x] = tot;
  }
}

__global__ __launch_bounds__(1024) void k_scan23(const int* __restrict__ bsum,
    int* __restrict__ rowptr, int nb, int n)
{
  int b = blockIdx.x;
  int t = threadIdx.x;
  int off = 0;
  for (int j = 0; j < b; j++) off += bsum[j];
  int i = b * 1024 + t;
  if (i < n) rowptr[i] += off;
  if (b == 0 && t == 0) {
    int tot = 0;
    for (int j = 0; j < nb; j++) tot += bsum[j];
    rowptr[n] = tot;
  }
}

// CSR fill
__global__ __launch_bounds__(256) void k_fill(const int* __restrict__ src,
    const int* __restrict__ dst, const int* __restrict__ rowptr,
    int* __restrict__ cnt, int* __restrict__ eid, int* __restrict__ srcs,
    int* __restrict__ perm, int E)
{
  int e = blockIdx.x * 256 + threadIdx.x;
  if (e < E) {
    int d = dst[e];
    int pos = rowptr[d] + atomicAdd(&cnt[d], 1);
    eid[pos] = e;
    srcs[pos] = src[e];
    perm[e] = pos;
  }
}

// a_edge for real edges, lane-owns-edge, weights broadcast from LDS.
__global__ __launch_bounds__(256) void k_aeg_e(const float* __restrict__ eattr,
    const float* __restrict__ we, const float* __restrict__ be,
    const float* __restrict__ vE, const int* __restrict__ perm,
    float* __restrict__ aeg1, float* __restrict__ aeg2, int E)
{
  __shared__ float4 we_t4[HID][4];
  __shared__ float4 vE_s[2][HID];
  __shared__ float  be_s[HID];
  int t = threadIdx.x;
  for (int i = t; i < FE * HID; i += 256) {
    int k = i >> 6, c = i & 63;
    ((float*)we_t4)[c * 16 + k] = we[i];
  }
  for (int i = t; i < 512; i += 256) ((float*)vE_s)[i] = vE[i];
  if (t < HID) be_s[t] = be[t];
  __syncthreads();

  int e = blockIdx.x * 256 + t;
  if (e >= E) return;
  const float4* er = (const float4*)(eattr + (size_t)e * FE);
  float4 A = er[0], B = er[1], C4 = er[2], D = er[3];
  float ta[FE] = {A.x, A.y, A.z, A.w, B.x, B.y, B.z, B.w,
                  C4.x, C4.y, C4.z, C4.w, D.x, D.y, D.z, D.w};
  float4 acc1 = make_float4(0.f, 0.f, 0.f, 0.f);
  float4 acc2 = make_float4(0.f, 0.f, 0.f, 0.f);
  #pragma unroll 4
  for (int c = 0; c < HID; c++) {
    float4 w0 = we_t4[c][0], w1 = we_t4[c][1], w2 = we_t4[c][2], w3 = we_t4[c][3];
    float ea = be_s[c];
    ea += ta[0] * w0.x + ta[1] * w0.y + ta[2] * w0.z + ta[3] * w0.w;
    ea += ta[4] * w1.x + ta[5] * w1.y + ta[6] * w1.z + ta[7] * w1.w;
    ea += ta[8] * w2.x + ta[9] * w2.y + ta[10] * w2.z + ta[11] * w2.w;
    ea += ta[12] * w3.x + ta[13] * w3.y + ta[14] * w3.z + ta[15] * w3.w;
    ea = fmaxf(ea, 0.f);
    float4 u1 = vE_s[0][c], u2 = vE_s[1][c];
    acc1.x += ea * u1.x; acc1.y += ea * u1.y; acc1.z += ea * u1.z; acc1.w += ea * u1.w;
    acc2.x += ea * u2.x; acc2.y += ea * u2.y; acc2.z += ea * u2.z; acc2.w += ea * u2.w;
  }
  int pos = perm[e];
  *(float4*)(aeg1 + (size_t)pos * 4) = acc1;
  *(float4*)(aeg2 + (size_t)pos * 4) = acc2;
}

// self-loop a_edge = segment-mean of CSR aeg values
__global__ __launch_bounds__(256) void k_self_aeg(const int* __restrict__ rowptr,
    float* __restrict__ aeg1, float* __restrict__ aeg2, int E, int n)
{
  int t = threadIdx.x;
  int v = blockIdx.x * 32 + (t >> 3);
  if (v >= n) return;
  int ent = t & 7;
  int h = ent & 3;
  const float* srcp = (ent < 4) ? aeg1 : aeg2;
  int r0 = rowptr[v], r1 = rowptr[v + 1];
  float s = 0.f;
  for (int j = r0; j < r1; j++) s += srcp[(size_t)j * 4 + h];
  float m = s / fmaxf((float)(r1 - r0), 1.f);
  if (ent < 4) aeg1[((size_t)E + v) * 4 + h] = m;
  else         aeg2[((size_t)E + v) * 4 + h] = m;
}

// h(bf16) = x @ lin [n,256]. 16 nodes/block; thread = 4 nodes x 4 channels.
__global__ __launch_bounds__(256) void k_h(const float* __restrict__ xin,
    const float* __restrict__ lin, unsigned short* __restrict__ h_bf, int n)
{
  int t = threadIdx.x, wv = t >> 6, lane = t & 63;
  int v0 = blockIdx.x * 16;
  __shared__ float xs[16][HID];
  {
    int node = t >> 4, ch4 = (t & 15) * 4;
    int vv = v0 + node;
    float4 val = make_float4(0.f, 0.f, 0.f, 0.f);
    if (vv < n) val = *(const float4*)(xin + (size_t)vv * HID + ch4);
    *(float4*)&xs[node][ch4] = val;
  }
  __syncthreads();
  float acc[4][4];
  #pragma unroll
  for (int i = 0; i < 4; i++)
    #pragma unroll
    for (int j = 0; j < 4; j++) acc[i][j] = 0.f;
  const float4* lin4 = (const float4*)lin;   // lin4[k*64 + c4]
  int nd0 = wv * 4;
  #pragma unroll 4
  for (int kb = 0; kb < 16; kb++) {
    float4 xv[4];
    #pragma unroll
    for (int i = 0; i < 4; i++) xv[i] = *(const float4*)&xs[nd0 + i][kb * 4];
    float4 lv0 = lin4[(kb * 4 + 0) * 64 + lane];
    float4 lv1 = lin4[(kb * 4 + 1) * 64 + lane];
    float4 lv2 = lin4[(kb * 4 + 2) * 64 + lane];
    float4 lv3 = lin4[(kb * 4 + 3) * 64 + lane];
    #pragma unroll
    for (int i = 0; i < 4; i++) {
      acc[i][0] += xv[i].x * lv0.x + xv[i].y * lv1.x + xv[i].z * lv2.x + xv[i].w * lv3.x;
      acc[i][1] += xv[i].x * lv0.y + xv[i].y * lv1.y + xv[i].z * lv2.y + xv[i].w * lv3.y;
      acc[i][2] += xv[i].x * lv0.z + xv[i].y * lv1.z + xv[i].z * lv2.z + xv[i].w * lv3.z;
      acc[i][3] += xv[i].x * lv0.w + xv[i].y * lv1.w + xv[i].z * lv2.w + xv[i].w * lv3.w;
    }
  }
  #pragma unroll
  for (int i = 0; i < 4; i++) {
    int v = v0 + nd0 + i;
    if (v < n) {
      uint2 u;
      u.x = pack2bf(acc[i][0], acc[i][1]);
      u.y = pack2bf(acc[i][2], acc[i][3]);
      *(uint2*)(h_bf + (size_t)v * 256 + lane * 4) = u;
    }
  }
}

// Fused per-node: softmax + alpha + aggregation + head-mean + bias + leaky +
// LayerNorm (+ optional fused next-layer att dots). WAVE per node.
template<bool DOTS>
__global__ __launch_bounds__(256) void k_node(
    const unsigned short* __restrict__ h_bf, const float* __restrict__ ssrc,
    const float* __restrict__ sdst, const float* __restrict__ aegc,
    const int* __restrict__ rowptr, const int* __restrict__ eidArr,
    const int* __restrict__ srcs, const float* __restrict__ bias,
    const float* __restrict__ gamma, const float* __restrict__ beta,
    const float* __restrict__ vS2, const float* __restrict__ vD2,
    float* __restrict__ alpha_out, float* __restrict__ xout,
    float* __restrict__ ssrc_o, float* __restrict__ sdst_o, int n, int E)
{
  __shared__ float als[4][4][64];   // [wave][head][slot]
  __shared__ int   svec[4][64];     // [wave][slot]
  int t = threadIdx.x; int wv = t >> 6, lane = t & 63;
  int v = blockIdx.x * 4 + wv;
  if (v >= n) return;
  int r0 = rowptr[v], r1 = rowptr[v + 1];
  int deg = r1 - r0, ne = deg + 1;      // + self loop (edge id E+v, src v)
  int coff = lane * 4;                  // aggregation: 4 channels per lane
  int hh = lane >> 4;                   // head owning those channels
  float acc0 = 0.f, acc1 = 0.f, acc2 = 0.f, acc3 = 0.f;
  const float4* aeg4 = (const float4*)aegc;
  const float4* ss4p = (const float4*)ssrc;
  float4 sd4 = ((const float4*)sdst)[v];

  if (ne <= 64) {
    // ---- lane = edge slot; all 4 heads per lane ----
    int s = v, eo = E + v;
    if (lane < deg) { s = srcs[r0 + lane]; eo = eidArr[r0 + lane]; }
    bool valid = (lane < ne);
    float a0 = -INFINITY, a1 = -INFINITY, a2 = -INFINITY, a3 = -INFINITY;
    if (valid) {
      float4 ae4 = aeg4[(lane < deg) ? (r0 + lane) : (E + v)];
      float4 ss4 = ss4p[s];
      a0 = ss4.x + sd4.x + ae4.x; a0 = (a0 > 0.f) ? a0 : 0.2f * a0;
      a1 = ss4.y + sd4.y + ae4.y; a1 = (a1 > 0.f) ? a1 : 0.2f * a1;
      a2 = ss4.z + sd4.z + ae4.z; a2 = (a2 > 0.f) ? a2 : 0.2f * a2;
      a3 = ss4.w + sd4.w + ae4.w; a3 = (a3 > 0.f) ? a3 : 0.2f * a3;
    }
    // ---- max reduce: array-halving ----
    float m0, m1, m2, m3;
    {
      bool hi0 = lane & 1;
      float k0 = hi0 ? a2 : a0, s0 = hi0 ? a0 : a2;
      float k1 = hi0 ? a3 : a1, s1 = hi0 ? a1 : a3;
      float q0 = fmaxf(k0, __shfl_xor(s0, 1));
      float q1 = fmaxf(k1, __shfl_xor(s1, 1));
      bool hi1 = lane & 2;
      float k2 = hi1 ? q1 : q0, s2 = hi1 ? q0 : q1;
      float r = fmaxf(k2, __shfl_xor(s2, 2));
      r = fmaxf(r, __shfl_xor(r, 4));
      r = fmaxf(r, __shfl_xor(r, 8));
      r = fmaxf(r, __shfl_xor(r, 16));
      r = fmaxf(r, __shfl_xor(r, 32));
      m0 = __shfl(r, 0); m1 = __shfl(r, 2); m2 = __shfl(r, 1); m3 = __shfl(r, 3);
    }
    float e0 = __expf(a0 - m0), e1 = __expf(a1 - m1);
    float e2 = __expf(a2 - m2), e3 = __expf(a3 - m3);
    float d0, d1, d2, d3;
    {
      bool hi0 = lane & 1;
      float k0 = hi0 ? e2 : e0, s0 = hi0 ? e0 : e2;
      float k1 = hi0 ? e3 : e1, s1 = hi0 ? e1 : e3;
      float q0 = k0 + __shfl_xor(s0, 1);
      float q1 = k1 + __shfl_xor(s1, 1);
      bool hi1 = lane & 2;
      float k2 = hi1 ? q1 : q0, s2 = hi1 ? q0 : q1;
      float r = k2 + __shfl_xor(s2, 2);
      r += __shfl_xor(r, 4);
      r += __shfl_xor(r, 8);
      r += __shfl_xor(r, 16);
      r += __shfl_xor(r, 32);
      d0 = __shfl(r, 0); d1 = __shfl(r, 2); d2 = __shfl(r, 1); d3 = __shfl(r, 3);
    }
    // invalid slots: e*=0 -> alpha 0 (den>0 since self-loop always present)
    float4 alf = make_float4(e0 / d0, e1 / d1, e2 / d2, e3 / d3);
    if (valid) {
      f32x4 alv = {alf.x, alf.y, alf.z, alf.w};
      __builtin_nontemporal_store(alv, (f32x4*)alpha_out + eo);
    }
    als[wv][0][lane] = alf.x;
    als[wv][1][lane] = alf.y;
    als[wv][2][lane] = alf.z;
    als[wv][3][lane] = alf.w;
    svec[wv][lane] = s;
    __builtin_amdgcn_wave_barrier();
    __builtin_amdgcn_sched_barrier(0);
    // ---- aggregation: tail-free, 8 loads in flight ----
    const float* alsh = als[wv][hh];
    const int* svp = svec[wv];
    for (int jj = 0; jj < ne; jj += 8) {
      int4 sv0 = *(const int4*)(svp + jj);
      int4 sv1 = *(const int4*)(svp + jj + 4);
      float4 al0 = *(const float4*)(alsh + jj);
      float4 al1 = *(const float4*)(alsh + jj + 4);
      uint2 u0 = *(const uint2*)(h_bf + (size_t)sv0.x * 256 + coff);
      uint2 u1 = *(const uint2*)(h_bf + (size_t)sv0.y * 256 + coff);
      uint2 u2 = *(const uint2*)(h_bf + (size_t)sv0.z * 256 + coff);
      uint2 u3 = *(const uint2*)(h_bf + (size_t)sv0.w * 256 + coff);
      uint2 u4 = *(const uint2*)(h_bf + (size_t)sv1.x * 256 + coff);
      uint2 u5 = *(const uint2*)(h_bf + (size_t)sv1.y * 256 + coff);
      uint2 u6 = *(const uint2*)(h_bf + (size_t)sv1.z * 256 + coff);
      uint2 u7 = *(const uint2*)(h_bf + (size_t)sv1.w * 256 + coff);
      acc0 += al0.x * bf2f((unsigned short)(u0.x & 0xffff))
            + al0.y * bf2f((unsigned short)(u1.x & 0xffff))
            + al0.z * bf2f((unsigned short)(u2.x & 0xffff))
            + al0.w * bf2f((unsigned short)(u3.x & 0xffff))
            + al1.x * bf2f((unsigned short)(u4.x & 0xffff))
            + al1.y * bf2f((unsigned short)(u5.x & 0xffff))
            + al1.z * bf2f((unsigned short)(u6.x & 0xffff))
            + al1.w * bf2f((unsigned short)(u7.x & 0xffff));
      acc1 += al0.x * bf2f((unsigned short)(u0.x >> 16))
            + al0.y * bf2f((unsigned short)(u1.x >> 16))
            + al0.z * bf2f((unsigned short)(u2.x >> 16))
            + al0.w * bf2f((unsigned short)(u3.x >> 16))
            + al1.x * bf2f((unsigned short)(u4.x >> 16))
            + al1.y * bf2f((unsigned short)(u5.x >> 16))
            + al1.z * bf2f((unsigned short)(u6.x >> 16))
            + al1.w * bf2f((unsigned short)(u7.x >> 16));
      acc2 += al0.x * bf2f((unsigned short)(u0.y & 0xffff))
            + al0.y * bf2f((unsigned short)(u1.y & 0xffff))
            + al0.z * bf2f((unsigned short)(u2.y & 0xffff))
            + al0.w * bf2f((unsigned short)(u3.y & 0xffff))
            + al1.x * bf2f((unsigned short)(u4.y & 0xffff))
            + al1.y * bf2f((unsigned short)(u5.y & 0xffff))
            + al1.z * bf2f((unsigned short)(u6.y & 0xffff))
            + al1.w * bf2f((unsigned short)(u7.y & 0xffff));
      acc3 += al0.x * bf2f((unsigned short)(u0.y >> 16))
            + al0.y * bf2f((unsigned short)(u1.y >> 16))
            + al0.z * bf2f((unsigned short)(u2.y >> 16))
            + al0.w * bf2f((unsigned short)(u3.y >> 16))
            + al1.x * bf2f((unsigned short)(u4.y >> 16))
            + al1.y * bf2f((unsigned short)(u5.y >> 16))
            + al1.z * bf2f((unsigned short)(u6.y >> 16))
            + al1.w * bf2f((unsigned short)(u7.y >> 16));
    }
  } else {
    // ---- chunked two-pass fallback (deg > 63, rare) ----
    int j4 = lane >> 2, hb = lane & 3;
    float sd = sdst[v * 4 + hb];
    float m = -INFINITY;
    for (int jb = 0; jb < ne; jb += 16) {
      int jc = jb + j4;
      if (jc < ne) {
        int s2 = (jc < deg) ? srcs[r0 + jc] : v;
        float ae = (jc < deg) ? aegc[(size_t)(r0 + jc) * 4 + hb]
                              : aegc[((size_t)E + v) * 4 + hb];
        float a = ssrc[s2 * 4 + hb] + sd + ae;
        a = (a > 0.f) ? a : 0.2f * a;
        m = fmaxf(m, a);
      }
    }
    m = fmaxf(m, __shfl_xor(m, 4));
    m = fmaxf(m, __shfl_xor(m, 8));
    m = fmaxf(m, __shfl_xor(m, 16));
    m = fmaxf(m, __shfl_xor(m, 32));
    float den = 0.f;
    for (int jb = 0; jb < ne; jb += 16) {
      int jc = jb + j4;
      if (jc < ne) {
        int s2 = (jc < deg) ? srcs[r0 + jc] : v;
        float ae = (jc < deg) ? aegc[(size_t)(r0 + jc) * 4 + hb]
                              : aegc[((size_t)E + v) * 4 + hb];
        float a = ssrc[s2 * 4 + hb] + sd + ae;
        a = (a > 0.f) ? a : 0.2f * a;
        den += __expf(a - m);
      }
    }
    den += __shfl_xor(den, 4);
    den += __shfl_xor(den, 8);
    den += __shfl_xor(den, 16);
    den += __shfl_xor(den, 32);
    float rden = 1.f / den;
    for (int jb = 0; jb < ne; jb += 16) {
      int jc = jb + j4;
      if (jc < ne) {
        int s2 = (jc < deg) ? srcs[r0 + jc] : v;
        int eo = (jc < deg) ? eidArr[r0 + jc] : E + v;
        float ae = (jc < deg) ? aegc[(size_t)(r0 + jc) * 4 + hb]
                              : aegc[((size_t)E + v) * 4 + hb];
        float a = ssrc[s2 * 4 + hb] + sd + ae;
        a = (a > 0.f) ? a : 0.2f * a;
        alpha_out[(size_t)eo * 4 + hb] = __expf(a - m) * rden;
      }
    }
    float sdh = __shfl(sd, hh);
    float mh  = __shfl(m, hh);
    float rdh = __shfl(rden, hh);
    for (int jc = 0; jc < ne; jc++) {
      int s0 = (jc < deg) ? srcs[r0 + jc] : v;
      size_t ap = (jc < deg) ? (size_t)(r0 + jc) : (size_t)E + v;
      float a = ssrc[s0 * 4 + hh] + sdh + aegc[ap * 4 + hh];
      a = (a > 0.f) ? a : 0.2f * a;
      float al = __expf(a - mh) * rdh;
      uint2 u = *(const uint2*)(h_bf + (size_t)s0 * 256 + coff);
      acc0 += al * bf2f((unsigned short)(u.x & 0xffff));
      acc1 += al * bf2f((unsigned short)(u.x >> 16));
      acc2 += al * bf2f((unsigned short)(u.y & 0xffff));
      acc3 += al * bf2f((unsigned short)(u.y >> 16));
    }
  }

  // ---- head reduce: lanes {L, L+16, L+32, L+48} hold heads 0..3 ----
  acc0 += __shfl_xor(acc0, 16); acc0 += __shfl_xor(acc0, 32);
  acc1 += __shfl_xor(acc1, 16); acc1 += __shfl_xor(acc1, 32);
  acc2 += __shfl_xor(acc2, 16); acc2 += __shfl_xor(acc2, 32);
  acc3 += __shfl_xor(acc3, 16); acc3 += __shfl_xor(acc3, 32);

  // ---- epilogue: bias + leaky(0.01) + LayerNorm(64); all lanes hold copy ----
  int c16 = lane & 15;
  float4 b4 = ((const float4*)bias)[c16];
  float v0 = acc0 * 0.25f + b4.x;
  float v1 = acc1 * 0.25f + b4.y;
  float v2 = acc2 * 0.25f + b4.z;
  float v3 = acc3 * 0.25f + b4.w;
  v0 = (v0 > 0.f) ? v0 : 0.01f * v0;
  v1 = (v1 > 0.f) ? v1 : 0.01f * v1;
  v2 = (v2 > 0.f) ? v2 : 0.01f * v2;
  v3 = (v3 > 0.f) ? v3 : 0.01f * v3;
  float mu = v0 + v1 + v2 + v3;
  mu += __shfl_xor(mu, 1); mu += __shfl_xor(mu, 2);
  mu += __shfl_xor(mu, 4); mu += __shfl_xor(mu, 8);
  mu *= (1.f / 64.f);
  float d0 = v0 - mu, d1 = v1 - mu, d2 = v2 - mu, d3 = v3 - mu;
  float var = d0 * d0 + d1 * d1 + d2 * d2 + d3 * d3;
  var += __shfl_xor(var, 1); var += __shfl_xor(var, 2);
  var += __shfl_xor(var, 4); var += __shfl_xor(var, 8);
  var *= (1.f / 64.f);
  float rstd = rsqrtf(var + 1e-5f);
  float4 g4 = ((const float4*)gamma)[c16];
  float4 be4 = ((const float4*)beta)[c16];
  float y0 = d0 * rstd * g4.x + be4.x;
  float y1 = d1 * rstd * g4.y + be4.y;
  float y2 = d2 * rstd * g4.z + be4.z;
  float y3 = d3 * rstd * g4.w + be4.w;
  if (lane < 16) {
    float4 y = make_float4(y0, y1, y2, y3);
    *(float4*)(xout + (size_t)v * HID + lane * 4) = y;
  }
  if constexpr (DOTS) {
    // next-layer att dots: p_h = y . vS2[:,h] (4 wave-copies -> scale 0.25)
    int c0 = c16 * 4;
    float4 vs0 = ((const float4*)vS2)[c0],     vs1 = ((const float4*)vS2)[c0 + 1];
    float4 vs2 = ((const float4*)vS2)[c0 + 2], vs3 = ((const float4*)vS2)[c0 + 3];
    float4 vd0 = ((const float4*)vD2)[c0],     vd1 = ((const float4*)vD2)[c0 + 1];
    float4 vd2 = ((const float4*)vD2)[c0 + 2], vd3 = ((const float4*)vD2)[c0 + 3];
    float p[8];
    p[0] = y0 * vs0.x + y1 * vs1.x + y2 * vs2.x + y3 * vs3.x;
    p[1] = y0 * vs0.y + y1 * vs1.y + y2 * vs2.y + y3 * vs3.y;
    p[2] = y0 * vs0.z + y1 * vs1.z + y2 * vs2.z + y3 * vs3.z;
    p[3] = y0 * vs0.w + y1 * vs1.w + y2 * vs2.w + y3 * vs3.w;
    p[4] = y0 * vd0.x + y1 * vd1.x + y2 * vd2.x + y3 * vd3.x;
    p[5] = y0 * vd0.y + y1 * vd1.y + y2 * vd2.y + y3 * vd3.y;
    p[6] = y0 * vd0.z + y1 * vd1.z + y2 * vd2.z + y3 * vd3.z;
    p[7] = y0 * vd0.w + y1 * vd1.w + y2 * vd2.w + y3 * vd3.w;
    reduce8_store(p, ssrc_o, sdst_o, (size_t)v, lane, 0.25f);
  }
}

extern "C" void kernel_launch(void* const* d_in, const int* in_sizes, int n_in,
                              void* d_out, int out_size, void* d_ws, size_t ws_size,
                              hipStream_t stream)
{
  const float* x     = (const float*)d_in[0];
  const int*   eidx  = (const int*)d_in[1];
  const float* eattr = (const float*)d_in[2];
  const float* wn    = (const float*)d_in[3];
  const float* bn    = (const float*)d_in[4];
  const float* we    = (const float*)d_in[5];
  const float* be    = (const float*)d_in[6];
  const float* lin1  = (const float*)d_in[7];
  const float* line1 = (const float*)d_in[8];
  const float* as1   = (const float*)d_in[9];
  const float* ad1   = (const float*)d_in[10];
  const float* ae1   = (const float*)d_in[11];
  const float* b1    = (const float*)d_in[12];
  const float* g1    = (const float*)d_in[13];
  const float* bt1   = (const float*)d_in[14];
  const float* lin2  = (const float*)d_in[15];
  const float* line2 = (const float*)d_in[16];
  const float* as2   = (const float*)d_in[17];
  const float* ad2   = (const float*)d_in[18];
  const float* ae2   = (const float*)d_in[19];
  const float* b2    = (const float*)d_in[20];
  const float* g2    = (const float*)d_in[21];
  const float* bt2   = (const float*)d_in[22];

  int n = in_sizes[0] / FN;
  int E = in_sizes[1] / 2;
  const int* srcA = eidx;
  const int* dstA = eidx + E;

  float* out_h2 = (float*)d_out;
  float* alpha1 = out_h2 + (size_t)n * HID;
  float* alpha2 = alpha1 + (size_t)(E + n) * 4;

  char* ws = (char*)d_ws;
  size_t off = 0;
  auto alloc = [&](size_t bytes) -> char* {
    char* p = ws + off;
    off += (bytes + 255) & ~(size_t)255;
    return p;
  };
  unsigned short* h_bf = (unsigned short*)alloc((size_t)n * 256 * 2);
  float* x1      = (float*)alloc((size_t)n * HID * 4);
  float* h1      = (float*)alloc((size_t)n * HID * 4);
  float* aeg1c   = (float*)alloc((size_t)(E + n) * 4 * 4);
  float* aeg2c   = (float*)alloc((size_t)(E + n) * 4 * 4);
  float* ssrc1   = (float*)alloc((size_t)n * 4 * 4);
  float* sdst1   = (float*)alloc((size_t)n * 4 * 4);
  float* ssrc2   = (float*)alloc((size_t)n * 4 * 4);
  float* sdst2   = (float*)alloc((size_t)n * 4 * 4);
  float* vS      = (float*)alloc(512 * 4);
  float* vD      = (float*)alloc(512 * 4);
  float* vE      = (float*)alloc(512 * 4);
  int*   deg     = (int*)alloc((size_t)n * 4);
  int*   cnt     = (int*)alloc((size_t)n * 4);
  int*   rowptr  = (int*)alloc((size_t)(n + 1) * 4);
  int*   eid     = (int*)alloc((size_t)E * 4);
  int*   srcs    = (int*)alloc((size_t)E * 4);
  int*   perm    = (int*)alloc((size_t)E * 4);
  int*   bsum    = (int*)alloc(1024 * 4);

  hipMemsetAsync(deg, 0, (size_t)n * 4, stream);
  hipMemsetAsync(cnt, 0, (size_t)n * 4, stream);

  int nb = (n + 1023) / 1024;
  k_vecs<<<6, 256, 0, stream>>>(lin1, line1, as1, ad1, ae1,
                                lin2, line2, as2, ad2, ae2, vS, vD, vE);
  k_x1<<<(n + 3) / 4, 256, 0, stream>>>(x, wn, bn, vS, vD, x1, ssrc1, sdst1, n);
  k_deg<<<(E + 255) / 256, 256, 0, stream>>>(dstA, deg, E);
  k_scan1<<<nb, 1024, 0, stream>>>(deg, rowptr, bsum, n);
  k_scan23<<<nb, 1024, 0, stream>>>(bsum, rowptr, nb, n);
  k_fill<<<(E + 255) / 256, 256, 0, stream>>>(srcA, dstA, rowptr, cnt, eid, srcs, perm, E);
  k_aeg_e<<<(E + 255) / 256, 256, 0, stream>>>(eattr, we, be, vE, perm, aeg1c, aeg2c, E);
  k_self_aeg<<<(n + 31) / 32, 256, 0, stream>>>(rowptr, aeg1c, aeg2c, E, n);

  // layer 1 (fuses layer-2 att dots into epilogue)
  k_h<<<(n + 15) / 16, 256, 0, stream>>>(x1, lin1, h_bf, n);
  k_node<true><<<(n + 3) / 4, 256, 0, stream>>>(h_bf, ssrc1, sdst1, aeg1c,
      rowptr, eid, srcs, b1, g1, bt1, vS + 256, vD + 256,
      alpha1, h1, ssrc2, sdst2, n, E);
  // layer 2
  k_h<<<(n + 15) / 16, 256, 0, stream>>>(h1, lin2, h_bf, n);
  k_node<false><<<(n + 3) / 4, 256, 0, stream>>>(h_bf, ssrc2, sdst2, aeg2c,
      rowptr, eid, srcs, b2, g2, bt2, nullptr, nullptr,
      alpha2, out_h2, nullptr, nullptr, n, E);
}